// Round 13
// baseline (201.414 us; speedup 1.0000x reference)
//
#include <hip/hip_runtime.h>
#include <math.h>

#define BSH 7              // 128 nodes per bucket
#define BSZ (1 << BSH)
#define MAXNB 256          // max buckets per side
#define PT_TILE 4096       // edges per partition block

typedef __attribute__((ext_vector_type(4))) float f32x4;
typedef __attribute__((ext_vector_type(8))) short bf16x8;

// f32 -> bf16 (round to nearest even)
__device__ __forceinline__ unsigned short f2b(float f) {
    unsigned u = __float_as_uint(f);
    return (unsigned short)((u + 0x7FFFu + ((u >> 16) & 1u)) >> 16);
}
__device__ __forceinline__ float blo(unsigned u) { return __uint_as_float(u << 16); }
__device__ __forceinline__ float bhi(unsigned u) { return __uint_as_float(u & 0xFFFF0000u); }

// ---------- prep: zero bucket counters + transposed bf16 weights ----------
__global__ void prep_kernel(const float* __restrict__ Wk, const float* __restrict__ Wv,
                            const float* __restrict__ Wo,
                            unsigned short* __restrict__ WkT, unsigned short* __restrict__ WvT,
                            unsigned short* __restrict__ WoT,
                            int* bcnt1, int* bcnt2, int nb1, int nb2) {
    int tid = threadIdx.x;
    for (int i = tid; i < nb1; i += blockDim.x) bcnt1[i] = 0;
    for (int i = tid; i < nb2; i += blockDim.x) bcnt2[i] = 0;
    for (int i = tid; i < 4096; i += blockDim.x) {
        int k = i >> 6, c = i & 63;
        WkT[c * 64 + k] = f2b(Wk[i]);
        WvT[c * 64 + k] = f2b(Wv[i]);
        WoT[c * 64 + k] = f2b(Wo[i]);
    }
}

// ---------- MFMA projections: K = bf16(X)@Wk, V = bf16(X)@Wv (both sides) ----------
// A frag: row = lane&15, k-slot (lane>>4, t); B frag: col = lane&15, same k-slot map.
// D frag: col = lane&15, row = (lane>>4)*4 + reg   [m89, verified in-harness R11/R12]
__global__ void proj_mfma_kernel(const float* __restrict__ X1, int n1,
                                 const float* __restrict__ X2, int n2,
                                 const unsigned short* __restrict__ WkT,
                                 const unsigned short* __restrict__ WvT,
                                 unsigned short* __restrict__ Kall,
                                 unsigned short* __restrict__ Vall) {
    int lane = threadIdx.x & 63;
    int wave = threadIdx.x >> 6;
    int wpb = blockDim.x >> 6;
    int total = n1 + n2;
    int ntiles = (total + 15) >> 4;
    int tile = blockIdx.x * wpb + wave;
    if (tile >= ntiles) return;
    int r0 = tile << 4;
    int rr = r0 + (lane & 15);
    if (rr > total - 1) rr = total - 1;      // tail guard (reads only)
    int kg = lane >> 4;
    int k0 = kg * 8;
    int c = lane & 15;
    const float* xp = (rr < n1) ? (X1 + (long)rr * 64) : (X2 + (long)(rr - n1) * 64);
    float4 xa = *(const float4*)(xp + k0);
    float4 xb = *(const float4*)(xp + k0 + 4);
    float4 xc = *(const float4*)(xp + k0 + 32);
    float4 xd = *(const float4*)(xp + k0 + 36);
    bf16x8 a0, a1;
    a0[0] = (short)f2b(xa.x); a0[1] = (short)f2b(xa.y);
    a0[2] = (short)f2b(xa.z); a0[3] = (short)f2b(xa.w);
    a0[4] = (short)f2b(xb.x); a0[5] = (short)f2b(xb.y);
    a0[6] = (short)f2b(xb.z); a0[7] = (short)f2b(xb.w);
    a1[0] = (short)f2b(xc.x); a1[1] = (short)f2b(xc.y);
    a1[2] = (short)f2b(xc.z); a1[3] = (short)f2b(xc.w);
    a1[4] = (short)f2b(xd.x); a1[5] = (short)f2b(xd.y);
    a1[6] = (short)f2b(xd.z); a1[7] = (short)f2b(xd.w);
    int orow0 = kg * 4;
#pragma unroll
    for (int n0 = 0; n0 < 64; n0 += 16) {
        bf16x8 bk0 = *(const bf16x8*)(WkT + (n0 + c) * 64 + k0);
        bf16x8 bk1 = *(const bf16x8*)(WkT + (n0 + c) * 64 + k0 + 32);
        bf16x8 bv0 = *(const bf16x8*)(WvT + (n0 + c) * 64 + k0);
        bf16x8 bv1 = *(const bf16x8*)(WvT + (n0 + c) * 64 + k0 + 32);
        f32x4 aK = {0.f, 0.f, 0.f, 0.f};
        f32x4 aV = {0.f, 0.f, 0.f, 0.f};
        aK = __builtin_amdgcn_mfma_f32_16x16x32_bf16(a0, bk0, aK, 0, 0, 0);
        aK = __builtin_amdgcn_mfma_f32_16x16x32_bf16(a1, bk1, aK, 0, 0, 0);
        aV = __builtin_amdgcn_mfma_f32_16x16x32_bf16(a0, bv0, aV, 0, 0, 0);
        aV = __builtin_amdgcn_mfma_f32_16x16x32_bf16(a1, bv1, aV, 0, 0, 0);
#pragma unroll
        for (int q = 0; q < 4; ++q) {
            int r = r0 + orow0 + q;
            if (r < total) {
                Kall[(long)r * 64 + n0 + c] = f2b(aK[q]);
                Vall[(long)r * 64 + n0 + c] = f2b(aV[q]);
            }
        }
    }
}

// ---------- fused edge logits + bucket histogram (grid-stride) ----------
__global__ void logit_count_kernel(const unsigned short* __restrict__ K1,
                                   const unsigned short* __restrict__ K2,
                                   const int* __restrict__ seg1, const int* __restrict__ seg2,
                                   float* __restrict__ trans, int E,
                                   int* bcnt1, int* bcnt2, int nb1, int nb2) {
    __shared__ int c1[MAXNB], c2[MAXNB];
    int tid = threadIdx.x;
    for (int i = tid; i < MAXNB; i += blockDim.x) { c1[i] = 0; c2[i] = 0; }
    __syncthreads();
    long totalT = (long)E * 8;
    long stride = (long)gridDim.x * blockDim.x;
    for (long t = (long)blockIdx.x * blockDim.x + tid; t < totalT; t += stride) {
        int e = (int)(t >> 3), g = (int)(t & 7);
        int i1 = seg1[e], i2 = seg2[e];
        uint4 a = *(const uint4*)(K1 + (long)i1 * 64 + g * 8);
        uint4 b = *(const uint4*)(K2 + (long)i2 * 64 + g * 8);
        float d = blo(a.x) * blo(b.x);
        d = fmaf(bhi(a.x), bhi(b.x), d);
        d = fmaf(blo(a.y), blo(b.y), d);
        d = fmaf(bhi(a.y), bhi(b.y), d);
        d = fmaf(blo(a.z), blo(b.z), d);
        d = fmaf(bhi(a.z), bhi(b.z), d);
        d = fmaf(blo(a.w), blo(b.w), d);
        d = fmaf(bhi(a.w), bhi(b.w), d);
        d += __shfl_xor(d, 1);
        d += __shfl_xor(d, 2);
        d += __shfl_xor(d, 4);
        if (g == 0) {
            trans[e] = d;
            atomicAdd(&c1[i1 >> BSH], 1);
            atomicAdd(&c2[i2 >> BSH], 1);
        }
    }
    __syncthreads();
    for (int i = tid; i < nb1; i += blockDim.x) if (c1[i]) atomicAdd(&bcnt1[i], c1[i]);
    for (int i = tid; i < nb2; i += blockDim.x) if (c2[i]) atomicAdd(&bcnt2[i], c2[i]);
}

// ---------- scan bucket counts (1 block, MAXNB threads) ----------
__global__ void bucket_scan_kernel(const int* __restrict__ bcnt1, const int* __restrict__ bcnt2,
                                   int* bb1, int* bb2, int* bcur1, int* bcur2,
                                   int nb1, int nb2, int E) {
    __shared__ int tmp[MAXNB];
    int t = threadIdx.x;
    int v1 = (t < nb1) ? bcnt1[t] : 0;
    tmp[t] = v1;
    __syncthreads();
    for (int off = 1; off < MAXNB; off <<= 1) {
        int x = (t >= off) ? tmp[t - off] : 0;
        __syncthreads();
        tmp[t] += x;
        __syncthreads();
    }
    if (t < nb1) { int excl = tmp[t] - v1; bb1[t] = excl; bcur1[t] = excl; }
    if (t == 0) bb1[nb1] = E;
    __syncthreads();
    int v2 = (t < nb2) ? bcnt2[t] : 0;
    tmp[t] = v2;
    __syncthreads();
    for (int off = 1; off < MAXNB; off <<= 1) {
        int x = (t >= off) ? tmp[t - off] : 0;
        __syncthreads();
        tmp[t] += x;
        __syncthreads();
    }
    if (t < nb2) { int excl = tmp[t] - v2; bb2[t] = excl; bcur2[t] = excl; }
    if (t == 0) bb2[nb2] = E;
}

// ---------- partition: emit (t, nodelocal<<25|j) records into bucket regions ----------
__global__ void partition_kernel(const int* __restrict__ seg1, const int* __restrict__ seg2,
                                 const float* __restrict__ trans, int E,
                                 int* bcur1, int* bcur2,
                                 float2* __restrict__ tmp1, float2* __restrict__ tmp2) {
    __shared__ int c1[MAXNB], c2[MAXNB];
    int tid = threadIdx.x;
    int base = blockIdx.x * PT_TILE;
    int end = base + PT_TILE;
    if (end > E) end = E;
    for (int i = tid; i < MAXNB; i += blockDim.x) { c1[i] = 0; c2[i] = 0; }
    __syncthreads();
    for (int i = base + tid; i < end; i += blockDim.x) {
        atomicAdd(&c1[seg1[i] >> BSH], 1);
        atomicAdd(&c2[seg2[i] >> BSH], 1);
    }
    __syncthreads();
    for (int i = tid; i < MAXNB; i += blockDim.x) {
        int n = c1[i]; c1[i] = n ? atomicAdd(&bcur1[i], n) : 0;
        n = c2[i];     c2[i] = n ? atomicAdd(&bcur2[i], n) : 0;
    }
    __syncthreads();
    for (int i = base + tid; i < end; i += blockDim.x) {
        int s1 = seg1[i], s2 = seg2[i];
        float t = trans[i];
        int p = atomicAdd(&c1[s1 >> BSH], 1);
        tmp1[p] = make_float2(t, __int_as_float(((s1 & (BSZ - 1)) << 25) | s2));
        int q = atomicAdd(&c2[s2 >> BSH], 1);
        tmp2[q] = make_float2(t, __int_as_float(((s2 & (BSZ - 1)) << 25) | s1));
    }
}

// ---------- bin2 (fused both sides): bucket records -> node-sorted CSR (t, j) ----------
__global__ void bin2_kernel(const float2* __restrict__ tmp1, const int* __restrict__ bb1,
                            int n1, int* __restrict__ cur1, int* __restrict__ deg1,
                            float2* __restrict__ csr1,
                            const float2* __restrict__ tmp2, const int* __restrict__ bb2,
                            int n2, int* __restrict__ cur2, int* __restrict__ deg2,
                            float2* __restrict__ csr2, int nb1) {
    __shared__ int cnt[BSZ];
    __shared__ int off[BSZ];
    __shared__ int sc[BSZ];
    int b = blockIdx.x;
    const float2* tmp; const int* bb; int n; int* cur; int* deg; float2* csr;
    if (b < nb1) { tmp = tmp1; bb = bb1; n = n1; cur = cur1; deg = deg1; csr = csr1; }
    else { b -= nb1; tmp = tmp2; bb = bb2; n = n2; cur = cur2; deg = deg2; csr = csr2; }
    int tid = threadIdx.x;
    int node0 = b << BSH;
    int s = bb[b], e_end = bb[b + 1];
    for (int i = tid; i < BSZ; i += blockDim.x) cnt[i] = 0;
    __syncthreads();
    for (int i = s + tid; i < e_end; i += blockDim.x)
        atomicAdd(&cnt[((unsigned)__float_as_int(tmp[i].y)) >> 25], 1);
    __syncthreads();
    if (tid < BSZ) sc[tid] = cnt[tid];
    __syncthreads();
    for (int o = 1; o < BSZ; o <<= 1) {
        int x = (tid >= o && tid < BSZ) ? sc[tid - o] : 0;
        __syncthreads();
        if (tid < BSZ) sc[tid] += x;
        __syncthreads();
    }
    if (tid < BSZ) {
        int excl = sc[tid] - cnt[tid] + s;
        off[tid] = excl;
        int node = node0 + tid;
        if (node < n) { cur[node] = excl; deg[node] = cnt[tid]; }
    }
    __syncthreads();
    for (int i = s + tid; i < e_end; i += blockDim.x) {
        float2 r = tmp[i];
        unsigned pay = (unsigned)__float_as_int(r.y);
        int pos = atomicAdd(&off[pay >> 25], 1);
        csr[pos] = make_float2(r.x, __int_as_float((int)(pay & 0x1FFFFFFu)));
    }
}

// ---------- gather (LDS-free): softmax + packed-broadcast bf16 V gather -> bf16 raw msg ----------
__global__ void gather_ms_kernel(int n1, int n2,
                                 const int* __restrict__ cur1, const int* __restrict__ deg1,
                                 const float2* __restrict__ csr1,
                                 const unsigned short* __restrict__ Vb2,
                                 float2* __restrict__ minv1,
                                 const int* __restrict__ cur2, const int* __restrict__ deg2,
                                 const float2* __restrict__ csr2,
                                 const unsigned short* __restrict__ Vb1,
                                 float2* __restrict__ minv2,
                                 unsigned short* __restrict__ msgr,   // (n1+n2)*64 bf16, concat rows
                                 float invT) {
    int tid = threadIdx.x;
    int wave = tid >> 6, lane = tid & 63;
    int wpb = blockDim.x >> 6;
    int g = lane >> 4, l = lane & 15;
    int total = n1 + n2;
    for (int idx = blockIdx.x * wpb + wave; idx < total; idx += gridDim.x * wpb) {
        const int *cur, *deg; const float2* csr; const unsigned short* V;
        float2* minv; int nd;
        if (idx < n1) {
            cur = cur1; deg = deg1; csr = csr1; V = Vb2; minv = minv1; nd = idx;
        } else {
            cur = cur2; deg = deg2; csr = csr2; V = Vb1; minv = minv2; nd = idx - n1;
        }
        int d = deg[nd];
        int start = cur[nd];
        float4 acc = make_float4(0.f, 0.f, 0.f, 0.f);
        if (d > 0) {
            float t0 = -INFINITY, t1 = -INFINITY, t2 = -INFINITY;
            int j0 = 0, j1 = 0, j2 = 0;
            if (lane < d)       { float2 r = csr[start + lane];       t0 = r.x; j0 = __float_as_int(r.y); }
            if (lane + 64 < d)  { float2 r = csr[start + lane + 64];  t1 = r.x; j1 = __float_as_int(r.y); }
            if (lane + 128 < d) { float2 r = csr[start + lane + 128]; t2 = r.x; j2 = __float_as_int(r.y); }
            float m = fmaxf(fmaxf(t0, t1), t2);
            for (int k = 192 + lane; k < d; k += 64) m = fmaxf(m, csr[start + k].x);
            m = fmaxf(m, __shfl_xor(m, 1));
            m = fmaxf(m, __shfl_xor(m, 2));
            m = fmaxf(m, __shfl_xor(m, 4));
            m = fmaxf(m, __shfl_xor(m, 8));
            m = fmaxf(m, __shfl_xor(m, 16));
            m = fmaxf(m, __shfl_xor(m, 32));
            float p0 = (lane < d)       ? __expf((t0 - m) * invT) : 0.f;
            float p1 = (lane + 64 < d)  ? __expf((t1 - m) * invT) : 0.f;
            float p2 = (lane + 128 < d) ? __expf((t2 - m) * invT) : 0.f;
            float s = p0 + p1 + p2;
            for (int k = 192 + lane; k < d; k += 64) s += __expf((csr[start + k].x - m) * invT);
            s += __shfl_xor(s, 1);
            s += __shfl_xor(s, 2);
            s += __shfl_xor(s, 4);
            s += __shfl_xor(s, 8);
            s += __shfl_xor(s, 16);
            s += __shfl_xor(s, 32);
            float inv = 1.f / (s + 1e-8f);
            if (lane == 0) minv[nd] = make_float2(m, inv);
            // pack (w bf16)<<16 | j16 -> one shfl per edge
            unsigned u0 = ((unsigned)f2b(p0 * inv) << 16) | (unsigned)j0;
            unsigned u1 = ((unsigned)f2b(p1 * inv) << 16) | (unsigned)j1;
            unsigned u2 = ((unsigned)f2b(p2 * inv) << 16) | (unsigned)j2;
            int c0 = d < 64 ? d : 64;
#pragma unroll 8
            for (int k = 0; k < c0; k += 4) {
                unsigned u = (unsigned)__shfl((int)u0, k + g);
                float w = bhi(u);
                int j = (int)(u & 0xFFFFu);
                uint2 v = *(const uint2*)(V + (long)j * 64 + l * 4);
                acc.x = fmaf(w, blo(v.x), acc.x);
                acc.y = fmaf(w, bhi(v.x), acc.y);
                acc.z = fmaf(w, blo(v.y), acc.z);
                acc.w = fmaf(w, bhi(v.y), acc.w);
            }
            if (d > 64) {
                int c1 = (d - 64) < 64 ? (d - 64) : 64;
#pragma unroll 8
                for (int k = 0; k < c1; k += 4) {
                    unsigned u = (unsigned)__shfl((int)u1, k + g);
                    float w = bhi(u);
                    int j = (int)(u & 0xFFFFu);
                    uint2 v = *(const uint2*)(V + (long)j * 64 + l * 4);
                    acc.x = fmaf(w, blo(v.x), acc.x);
                    acc.y = fmaf(w, bhi(v.x), acc.y);
                    acc.z = fmaf(w, blo(v.y), acc.z);
                    acc.w = fmaf(w, bhi(v.y), acc.w);
                }
            }
            if (d > 128) {
                int c2 = (d - 128) < 64 ? (d - 128) : 64;
#pragma unroll 8
                for (int k = 0; k < c2; k += 4) {
                    unsigned u = (unsigned)__shfl((int)u2, k + g);
                    float w = bhi(u);
                    int j = (int)(u & 0xFFFFu);
                    uint2 v = *(const uint2*)(V + (long)j * 64 + l * 4);
                    acc.x = fmaf(w, blo(v.x), acc.x);
                    acc.y = fmaf(w, bhi(v.x), acc.y);
                    acc.z = fmaf(w, blo(v.y), acc.z);
                    acc.w = fmaf(w, bhi(v.y), acc.w);
                }
            }
            for (int base = 192; base < d; base += 64) {
                int k = base + lane;
                unsigned ur = 0;
                if (k < d) {
                    float2 r = csr[start + k];
                    float wr = __expf((r.x - m) * invT) * inv;
                    ur = ((unsigned)f2b(wr) << 16) | (unsigned)(__float_as_int(r.y) & 0xFFFF);
                }
                int cc = (d - base) < 64 ? (d - base) : 64;
                for (int k2 = 0; k2 < cc; k2 += 4) {
                    unsigned u = (unsigned)__shfl((int)ur, k2 + g);
                    float w = bhi(u);
                    int j = (int)(u & 0xFFFFu);
                    uint2 v = *(const uint2*)(V + (long)j * 64 + l * 4);
                    acc.x = fmaf(w, blo(v.x), acc.x);
                    acc.y = fmaf(w, bhi(v.x), acc.y);
                    acc.z = fmaf(w, blo(v.y), acc.z);
                    acc.w = fmaf(w, bhi(v.y), acc.w);
                }
            }
            acc.x += __shfl_xor(acc.x, 16); acc.y += __shfl_xor(acc.y, 16);
            acc.z += __shfl_xor(acc.z, 16); acc.w += __shfl_xor(acc.w, 16);
            acc.x += __shfl_xor(acc.x, 32); acc.y += __shfl_xor(acc.y, 32);
            acc.z += __shfl_xor(acc.z, 32); acc.w += __shfl_xor(acc.w, 32);
        }
        // group 0 writes the raw row as bf16 (coalesced 8B per lane)
        if (g == 0) {
            uint2 p;
            p.x = (unsigned)f2b(acc.x) | ((unsigned)f2b(acc.y) << 16);
            p.y = (unsigned)f2b(acc.z) | ((unsigned)f2b(acc.w) << 16);
            *(uint2*)(msgr + (long)idx * 64 + l * 4) = p;
        }
    }
}

// ---------- fused tail: MFMA output projection + coalesced edge weights ----------
// Blocks [0, outBlocks) do out = leaky(msgr @ Wo + bo); rest do e1/e2.
__global__ void tail_kernel(const unsigned short* __restrict__ msgr,
                            float* __restrict__ outp,
                            const unsigned short* __restrict__ WoT,
                            const float* __restrict__ bo, int total, int outBlocks,
                            const float* __restrict__ trans,
                            const int* __restrict__ seg1, const int* __restrict__ seg2,
                            const float2* __restrict__ minv1, const float2* __restrict__ minv2,
                            float* __restrict__ e1, float* __restrict__ e2,
                            int E, float invT) {
    if ((int)blockIdx.x < outBlocks) {
        int lane = threadIdx.x & 63;
        int wave = threadIdx.x >> 6;
        int wpb = blockDim.x >> 6;
        int ntiles = (total + 15) >> 4;
        int tile = blockIdx.x * wpb + wave;
        if (tile >= ntiles) return;
        int r0 = tile << 4;
        int rr = r0 + (lane & 15);
        if (rr > total - 1) rr = total - 1;       // tail guard (reads only)
        int kg = lane >> 4;
        int k0 = kg * 8;
        int c = lane & 15;
        const unsigned short* pr = msgr + (long)rr * 64;
        bf16x8 a0 = *(const bf16x8*)(pr + k0);
        bf16x8 a1 = *(const bf16x8*)(pr + k0 + 32);
        int orow0 = kg * 4;
#pragma unroll
        for (int n0 = 0; n0 < 64; n0 += 16) {
            bf16x8 b0 = *(const bf16x8*)(WoT + (n0 + c) * 64 + k0);
            bf16x8 b1 = *(const bf16x8*)(WoT + (n0 + c) * 64 + k0 + 32);
            f32x4 acc = {0.f, 0.f, 0.f, 0.f};
            acc = __builtin_amdgcn_mfma_f32_16x16x32_bf16(a0, b0, acc, 0, 0, 0);
            acc = __builtin_amdgcn_mfma_f32_16x16x32_bf16(a1, b1, acc, 0, 0, 0);
            float bias = bo[n0 + c];
#pragma unroll
            for (int q = 0; q < 4; ++q) {
                int r = r0 + orow0 + q;
                if (r < total) {
                    float o = acc[q] + bias;
                    o = (o >= 0.f) ? o : 0.01f * o;
                    outp[(long)r * 64 + n0 + c] = o;
                }
            }
        }
    } else {
        int e = (blockIdx.x - outBlocks) * blockDim.x + threadIdx.x;
        if (e >= E) return;
        float t = trans[e];
        float2 a = minv1[seg1[e]];
        float2 b = minv2[seg2[e]];
        e1[e] = __expf((t - a.x) * invT) * a.y;
        e2[e] = __expf((t - b.x) * invT) * b.y;
    }
}

// ---------- fallback path kernels (R2-proven, f32) ----------
__global__ void proj1_kernel(const float* __restrict__ X, int N,
                             const float* __restrict__ Wk,
                             const float* __restrict__ Wv,
                             float* __restrict__ K, float* __restrict__ V) {
    __shared__ float sWk[64 * 64];
    __shared__ float sWv[64 * 64];
    int tid = threadIdx.x;
    for (int i = tid; i < 4096; i += blockDim.x) { sWk[i] = Wk[i]; sWv[i] = Wv[i]; }
    __syncthreads();
    int wave = tid >> 6, lane = tid & 63;
    int wpb = blockDim.x >> 6;
    for (int n = blockIdx.x * wpb + wave; n < N; n += gridDim.x * wpb) {
        float x = X[n * 64 + lane];
        float ak = 0.f, av = 0.f;
#pragma unroll
        for (int k = 0; k < 64; ++k) {
            float xv = __shfl(x, k);
            ak = fmaf(xv, sWk[k * 64 + lane], ak);
            av = fmaf(xv, sWv[k * 64 + lane], av);
        }
        K[n * 64 + lane] = ak;
        V[n * 64 + lane] = av;
    }
}
__global__ void logit1_kernel(const float* __restrict__ K1, const float* __restrict__ K2,
                              const int* __restrict__ seg1, const int* __restrict__ seg2,
                              float* __restrict__ trans, int E) {
    int tid = blockIdx.x * blockDim.x + threadIdx.x;
    int e = tid >> 4, g = tid & 15;
    if (e >= E) return;
    int i1 = seg1[e], i2 = seg2[e];
    float4 a = ((const float4*)(K1 + (long)i1 * 64))[g];
    float4 b = ((const float4*)(K2 + (long)i2 * 64))[g];
    float d = a.x * b.x + a.y * b.y + a.z * b.z + a.w * b.w;
    d += __shfl_xor(d, 1);
    d += __shfl_xor(d, 2);
    d += __shfl_xor(d, 4);
    d += __shfl_xor(d, 8);
    if (g == 0) trans[e] = d;
}
__global__ void zero_deg_kernel(int* d1, int* d2, int n1, int n2) {
    int i = blockIdx.x * blockDim.x + threadIdx.x;
    if (i < n1) d1[i] = 0;
    if (i < n2) d2[i] = 0;
}
__global__ void hist_kernel(const int* __restrict__ seg1, const int* __restrict__ seg2,
                            int* deg1, int* deg2, int E) {
    int e = blockIdx.x * blockDim.x + threadIdx.x;
    if (e >= E) return;
    atomicAdd(&deg1[seg1[e]], 1);
    atomicAdd(&deg2[seg2[e]], 1);
}
__global__ void scan2_kernel(const int* __restrict__ d1, int* __restrict__ c1, int n1,
                             const int* __restrict__ d2, int* __restrict__ c2, int n2) {
    const int* deg = blockIdx.x ? d2 : d1;
    int* cur = blockIdx.x ? c2 : c1;
    int n = blockIdx.x ? n2 : n1;
    __shared__ int tmp[1024];
    __shared__ int s_carry;
    int t = threadIdx.x;
    if (t == 0) s_carry = 0;
    __syncthreads();
    for (int base = 0; base < n; base += 1024) {
        int idx = base + t;
        int v = (idx < n) ? deg[idx] : 0;
        tmp[t] = v;
        __syncthreads();
        for (int off = 1; off < 1024; off <<= 1) {
            int x = (t >= off) ? tmp[t - off] : 0;
            __syncthreads();
            tmp[t] += x;
            __syncthreads();
        }
        int excl = tmp[t] - v + s_carry;
        if (idx < n) cur[idx] = excl;
        __syncthreads();
        if (t == 0) s_carry += tmp[1023];
        __syncthreads();
    }
}
__global__ void bin_kernel(const int* __restrict__ seg1, const int* __restrict__ seg2,
                           int* cur1, int* cur2,
                           int* __restrict__ el1, int* __restrict__ el2, int E) {
    int e = blockIdx.x * blockDim.x + threadIdx.x;
    if (e >= E) return;
    int p1 = atomicAdd(&cur1[seg1[e]], 1);
    el1[p1] = e;
    int p2 = atomicAdd(&cur2[seg2[e]], 1);
    el2[p2] = e;
}
__global__ void gather_out_kernel(int N, const int* __restrict__ cur, const int* __restrict__ deg,
                                  const int* __restrict__ el, const float* __restrict__ trans,
                                  const int* __restrict__ segOther, const float* __restrict__ Vother,
                                  float* __restrict__ e_out, float* __restrict__ msg_out,
                                  const float* __restrict__ Wo, const float* __restrict__ bo,
                                  float invT) {
    __shared__ float sW[64 * 64];
    int tid = threadIdx.x;
    for (int i = tid; i < 4096; i += blockDim.x) sW[i] = Wo[i];
    __syncthreads();
    int wave = tid >> 6, lane = tid & 63;
    int wpb = blockDim.x >> 6;
    int node = blockIdx.x * wpb + wave;
    if (node >= N) return;
    int d = deg[node];
    int start = cur[node] - d;
    float acc = 0.f;
    if (d > 0) {
        float m = -INFINITY;
        for (int k = lane; k < d; k += 64) m = fmaxf(m, trans[el[start + k]]);
        m = fmaxf(m, __shfl_xor(m, 1));
        m = fmaxf(m, __shfl_xor(m, 2));
        m = fmaxf(m, __shfl_xor(m, 4));
        m = fmaxf(m, __shfl_xor(m, 8));
        m = fmaxf(m, __shfl_xor(m, 16));
        m = fmaxf(m, __shfl_xor(m, 32));
        float s = 0.f;
        for (int k = lane; k < d; k += 64) s += __expf((trans[el[start + k]] - m) * invT);
        s += __shfl_xor(s, 1);
        s += __shfl_xor(s, 2);
        s += __shfl_xor(s, 4);
        s += __shfl_xor(s, 8);
        s += __shfl_xor(s, 16);
        s += __shfl_xor(s, 32);
        float inv = 1.f / (s + 1e-8f);
        for (int base = 0; base < d; base += 64) {
            int k = base + lane;
            float w = 0.f;
            int j = 0;
            if (k < d) {
                int e = el[start + k];
                w = __expf((trans[e] - m) * invT) * inv;
                e_out[e] = w;
                j = segOther[e];
            }
            int cnt = (d - base < 64) ? (d - base) : 64;
            for (int q = 0; q < cnt; ++q) {
                float wq = __shfl(w, q);
                int jq = __shfl(j, q);
                acc = fmaf(wq, Vother[(long)jq * 64 + lane], acc);
            }
        }
    }
    float o = bo[lane];
#pragma unroll
    for (int k = 0; k < 64; ++k) {
        float xv = __shfl(acc, k);
        o = fmaf(xv, sW[k * 64 + lane], o);
    }
    o = (o >= 0.f) ? o : 0.01f * o;
    msg_out[(long)node * 64 + lane] = o;
}

extern "C" void kernel_launch(void* const* d_in, const int* in_sizes, int n_in,
                              void* d_out, int out_size, void* d_ws, size_t ws_size,
                              hipStream_t stream) {
    const float* node1 = (const float*)d_in[0];
    const int* seg1 = (const int*)d_in[1];
    const float* node2 = (const float*)d_in[3];
    const int* seg2 = (const int*)d_in[4];
    const float* Wk = (const float*)d_in[6];
    const float* Wv = (const float*)d_in[7];
    const float* Wo = (const float*)d_in[8];
    const float* bo = (const float*)d_in[9];

    int n1 = in_sizes[0] / 64;
    int n2 = in_sizes[3] / 64;
    int E = in_sizes[1];

    float* out = (float*)d_out;
    float* msg1 = out;
    float* msg2 = msg1 + (long)n1 * 64;
    float* e1 = msg2 + (long)n2 * 64;
    float* e2 = e1 + E;

    const float invT = 1.0f / sqrtf(64.0f);
    int nb1 = (n1 + BSZ - 1) >> BSH;
    int nb2 = (n2 + BSZ - 1) >> BSH;
    long Epad = (E + 1) & ~1L;

    // ---- fast-path layout (weights first for 16B alignment; bf16 K/V/msg) ----
    float* ws = (float*)d_ws;
    unsigned short* WkT = (unsigned short*)ws;          // 4096 ushort
    unsigned short* WvT = WkT + 4096;                   // 4096
    unsigned short* WoT = WvT + 4096;                   // 4096
    float2* csr1 = (float2*)(ws + 6144);                // E records
    float2* csr2 = csr1 + E;                            // E
    float2* tmp1 = csr2 + E;                            // E
    float2* tmp2 = tmp1 + E;                            // E
    float* trans = (float*)(tmp2 + E);                  // Epad
    float2* minv1 = (float2*)(trans + Epad);            // n1
    float2* minv2 = minv1 + n1;                         // n2
    unsigned short* Kb1 = (unsigned short*)(minv2 + n2);// n1*64 ushort
    unsigned short* Kb2 = Kb1 + (long)n1 * 64;          // n2*64
    unsigned short* Vb1 = Kb2 + (long)n2 * 64;          // n1*64
    unsigned short* Vb2 = Vb1 + (long)n1 * 64;          // n2*64
    unsigned short* msgr = Vb2 + (long)n2 * 64;         // (n1+n2)*64 ushort
    int* deg1 = (int*)(msgr + (long)(n1 + n2) * 64);    // n1
    int* deg2 = deg1 + n1;                              // n2
    int* cur1 = deg2 + n2;                              // n1
    int* cur2 = cur1 + n1;                              // n2
    int* bb1 = cur2 + n2;                               // nb1+1
    int* bb2 = bb1 + nb1 + 1;                           // nb2+1
    int* bcur1 = bb2 + nb2 + 1;                         // nb1
    int* bcur2 = bcur1 + nb1;                           // nb2
    int* bcnt1 = bcur2 + nb2;                           // nb1
    int* bcnt2 = bcnt1 + nb1;                           // nb2
    long fp_words = 6144 + 8L * E + Epad + 2L * (n1 + n2)
                  + 64L * (n1 + n2)                     // bf16 K,V both sides
                  + 32L * (n1 + n2)                     // bf16 raw msg
                  + 2L * (n1 + n2)                      // deg, cur
                  + 3L * (nb1 + nb2) + 2;
    bool fast = (E <= (1 << 20)) && (nb1 <= MAXNB) && (nb2 <= MAXNB)
             && (n1 < 65536) && (n2 < 65536) && (n1 + n2 > 0)
             && ((size_t)fp_words * 4 <= ws_size);

    if (fast) {
        int total = n1 + n2;
        int ntiles = (total + 15) / 16;
        int gg = (total + 3) / 4;
        if (gg > 2048) gg = 2048;
        prep_kernel<<<1, 256, 0, stream>>>(Wk, Wv, Wo, WkT, WvT, WoT,
                                           bcnt1, bcnt2, nb1, nb2);
        proj_mfma_kernel<<<(ntiles + 3) / 4, 256, 0, stream>>>(
            node1, n1, node2, n2, WkT, WvT, Kb1, Vb1);
        {
            long threads = (long)E * 8;
            int blocks = (int)((threads + 255) / 256);
            if (blocks > 2048) blocks = 2048;
            logit_count_kernel<<<blocks, 256, 0, stream>>>(
                Kb1, Kb2, seg1, seg2, trans, E, bcnt1, bcnt2, nb1, nb2);
        }
        bucket_scan_kernel<<<1, MAXNB, 0, stream>>>(bcnt1, bcnt2, bb1, bb2, bcur1, bcur2,
                                                    nb1, nb2, E);
        partition_kernel<<<(E + PT_TILE - 1) / PT_TILE, 256, 0, stream>>>(
            seg1, seg2, trans, E, bcur1, bcur2, tmp1, tmp2);
        bin2_kernel<<<nb1 + nb2, 256, 0, stream>>>(tmp1, bb1, n1, cur1, deg1, csr1,
                                                   tmp2, bb2, n2, cur2, deg2, csr2, nb1);
        gather_ms_kernel<<<gg, 256, 0, stream>>>(
            n1, n2, cur1, deg1, csr1, Vb2, minv1,
            cur2, deg2, csr2, Vb1, minv2, msgr, invT);
        {
            int outBlocks = (ntiles + 3) / 4;
            int edgeBlocks = (E + 255) / 256;
            tail_kernel<<<outBlocks + edgeBlocks, 256, 0, stream>>>(
                msgr, msg1, WoT, bo, total, outBlocks,
                trans, seg1, seg2, minv1, minv2, e1, e2, E, invT);
        }
    } else {
        // fallback: R2-proven f32 path
        float* K1f = ws;
        float* V1f = K1f + (long)n1 * 64;
        float* K2f = V1f + (long)n1 * 64;
        float* V2f = K2f + (long)n2 * 64;
        float* transf = V2f + (long)n2 * 64;
        int* deg1f = (int*)(transf + E);
        int* deg2f = deg1f + n1;
        int* cur1f = deg2f + n2;
        int* cur2f = cur1f + n1;
        int* el1 = (int*)K1f;
        int* el2 = (int*)K2f;

        proj1_kernel<<<(n1 + 3) / 4, 256, 0, stream>>>(node1, n1, Wk, Wv, K1f, V1f);
        proj1_kernel<<<(n2 + 3) / 4, 256, 0, stream>>>(node2, n2, Wk, Wv, K2f, V2f);
        {
            long threads = (long)E * 16;
            int blocks = (int)((threads + 255) / 256);
            logit1_kernel<<<blocks, 256, 0, stream>>>(K1f, K2f, seg1, seg2, transf, E);
        }
        zero_deg_kernel<<<((n1 > n2 ? n1 : n2) + 255) / 256, 256, 0, stream>>>(deg1f, deg2f, n1, n2);
        hist_kernel<<<(E + 255) / 256, 256, 0, stream>>>(seg1, seg2, deg1f, deg2f, E);
        scan2_kernel<<<2, 1024, 0, stream>>>(deg1f, cur1f, n1, deg2f, cur2f, n2);
        bin_kernel<<<(E + 255) / 256, 256, 0, stream>>>(seg1, seg2, cur1f, cur2f, el1, el2, E);

        gather_out_kernel<<<(n1 + 3) / 4, 256, 0, stream>>>(
            n1, cur1f, deg1f, el1, transf, seg2, V2f, e1, msg1, Wo, bo, invT);
        gather_out_kernel<<<(n2 + 3) / 4, 256, 0, stream>>>(
            n2, cur2f, deg2f, el2, transf, seg1, V1f, e2, msg2, Wo, bo, invT);
    }
}

// Round 14
// 172.666 us; speedup vs baseline: 1.1665x; 1.1665x over previous
//
#include <hip/hip_runtime.h>
#include <math.h>

#define BSH 7              // 128 nodes per bucket
#define BSZ (1 << BSH)
#define MAXNB 256          // max buckets per side
#define PT_TILE 4096       // edges per partition block

typedef __attribute__((ext_vector_type(4))) float f32x4;
typedef __attribute__((ext_vector_type(8))) short bf16x8;

// f32 -> bf16 (round to nearest even)
__device__ __forceinline__ unsigned short f2b(float f) {
    unsigned u = __float_as_uint(f);
    return (unsigned short)((u + 0x7FFFu + ((u >> 16) & 1u)) >> 16);
}
__device__ __forceinline__ float blo(unsigned u) { return __uint_as_float(u << 16); }
__device__ __forceinline__ float bhi(unsigned u) { return __uint_as_float(u & 0xFFFF0000u); }

// ---------- prep: zero bucket counters + transposed bf16 weights ----------
__global__ void prep_kernel(const float* __restrict__ Wk, const float* __restrict__ Wv,
                            const float* __restrict__ Wo,
                            unsigned short* __restrict__ WkT, unsigned short* __restrict__ WvT,
                            unsigned short* __restrict__ WoT,
                            int* bcnt1, int* bcnt2, int nb1, int nb2) {
    int tid = threadIdx.x;
    for (int i = tid; i < nb1; i += blockDim.x) bcnt1[i] = 0;
    for (int i = tid; i < nb2; i += blockDim.x) bcnt2[i] = 0;
    for (int i = tid; i < 4096; i += blockDim.x) {
        int k = i >> 6, c = i & 63;
        WkT[c * 64 + k] = f2b(Wk[i]);
        WvT[c * 64 + k] = f2b(Wv[i]);
        WoT[c * 64 + k] = f2b(Wo[i]);
    }
}

// ---------- MFMA projections: K = bf16(X)@Wk, V = bf16(X)@Wv (both sides) ----------
// A frag: row = lane&15, k-slot (lane>>4, t); B frag: col = lane&15, same k-slot map.
// D frag: col = lane&15, row = (lane>>4)*4 + reg   [m89, verified in-harness R11/R12]
__global__ void proj_mfma_kernel(const float* __restrict__ X1, int n1,
                                 const float* __restrict__ X2, int n2,
                                 const unsigned short* __restrict__ WkT,
                                 const unsigned short* __restrict__ WvT,
                                 unsigned short* __restrict__ Kall,
                                 unsigned short* __restrict__ Vall) {
    int lane = threadIdx.x & 63;
    int wave = threadIdx.x >> 6;
    int wpb = blockDim.x >> 6;
    int total = n1 + n2;
    int ntiles = (total + 15) >> 4;
    int tile = blockIdx.x * wpb + wave;
    if (tile >= ntiles) return;
    int r0 = tile << 4;
    int rr = r0 + (lane & 15);
    if (rr > total - 1) rr = total - 1;      // tail guard (reads only)
    int kg = lane >> 4;
    int k0 = kg * 8;
    int c = lane & 15;
    const float* xp = (rr < n1) ? (X1 + (long)rr * 64) : (X2 + (long)(rr - n1) * 64);
    float4 xa = *(const float4*)(xp + k0);
    float4 xb = *(const float4*)(xp + k0 + 4);
    float4 xc = *(const float4*)(xp + k0 + 32);
    float4 xd = *(const float4*)(xp + k0 + 36);
    bf16x8 a0, a1;
    a0[0] = (short)f2b(xa.x); a0[1] = (short)f2b(xa.y);
    a0[2] = (short)f2b(xa.z); a0[3] = (short)f2b(xa.w);
    a0[4] = (short)f2b(xb.x); a0[5] = (short)f2b(xb.y);
    a0[6] = (short)f2b(xb.z); a0[7] = (short)f2b(xb.w);
    a1[0] = (short)f2b(xc.x); a1[1] = (short)f2b(xc.y);
    a1[2] = (short)f2b(xc.z); a1[3] = (short)f2b(xc.w);
    a1[4] = (short)f2b(xd.x); a1[5] = (short)f2b(xd.y);
    a1[6] = (short)f2b(xd.z); a1[7] = (short)f2b(xd.w);
    int orow0 = kg * 4;
#pragma unroll
    for (int n0 = 0; n0 < 64; n0 += 16) {
        bf16x8 bk0 = *(const bf16x8*)(WkT + (n0 + c) * 64 + k0);
        bf16x8 bk1 = *(const bf16x8*)(WkT + (n0 + c) * 64 + k0 + 32);
        bf16x8 bv0 = *(const bf16x8*)(WvT + (n0 + c) * 64 + k0);
        bf16x8 bv1 = *(const bf16x8*)(WvT + (n0 + c) * 64 + k0 + 32);
        f32x4 aK = {0.f, 0.f, 0.f, 0.f};
        f32x4 aV = {0.f, 0.f, 0.f, 0.f};
        aK = __builtin_amdgcn_mfma_f32_16x16x32_bf16(a0, bk0, aK, 0, 0, 0);
        aK = __builtin_amdgcn_mfma_f32_16x16x32_bf16(a1, bk1, aK, 0, 0, 0);
        aV = __builtin_amdgcn_mfma_f32_16x16x32_bf16(a0, bv0, aV, 0, 0, 0);
        aV = __builtin_amdgcn_mfma_f32_16x16x32_bf16(a1, bv1, aV, 0, 0, 0);
#pragma unroll
        for (int q = 0; q < 4; ++q) {
            int r = r0 + orow0 + q;
            if (r < total) {
                Kall[(long)r * 64 + n0 + c] = f2b(aK[q]);
                Vall[(long)r * 64 + n0 + c] = f2b(aV[q]);
            }
        }
    }
}

// ---------- edge logits (bf16 K rows, 8 lanes/edge, 16B loads) ----------
__global__ void logit_kernel(const unsigned short* __restrict__ K1,
                             const unsigned short* __restrict__ K2,
                             const int* __restrict__ seg1, const int* __restrict__ seg2,
                             float* __restrict__ trans, int E) {
    int tid = blockIdx.x * blockDim.x + threadIdx.x;
    int e = tid >> 3, g = tid & 7;
    if (e >= E) return;
    int i1 = seg1[e], i2 = seg2[e];
    uint4 a = *(const uint4*)(K1 + (long)i1 * 64 + g * 8);
    uint4 b = *(const uint4*)(K2 + (long)i2 * 64 + g * 8);
    float d = blo(a.x) * blo(b.x);
    d = fmaf(bhi(a.x), bhi(b.x), d);
    d = fmaf(blo(a.y), blo(b.y), d);
    d = fmaf(bhi(a.y), bhi(b.y), d);
    d = fmaf(blo(a.z), blo(b.z), d);
    d = fmaf(bhi(a.z), bhi(b.z), d);
    d = fmaf(blo(a.w), blo(b.w), d);
    d = fmaf(bhi(a.w), bhi(b.w), d);
    d += __shfl_xor(d, 1);
    d += __shfl_xor(d, 2);
    d += __shfl_xor(d, 4);
    if (g == 0) trans[e] = d;
}

// ---------- bucket histogram ----------
__global__ void bucket_count_kernel(const int* __restrict__ seg1, const int* __restrict__ seg2,
                                    int E, int* bcnt1, int* bcnt2, int nb1, int nb2) {
    __shared__ int c1[MAXNB], c2[MAXNB];
    int tid = threadIdx.x;
    for (int i = tid; i < MAXNB; i += blockDim.x) { c1[i] = 0; c2[i] = 0; }
    __syncthreads();
    for (int i = blockIdx.x * blockDim.x + tid; i < E; i += gridDim.x * blockDim.x) {
        atomicAdd(&c1[seg1[i] >> BSH], 1);
        atomicAdd(&c2[seg2[i] >> BSH], 1);
    }
    __syncthreads();
    for (int i = tid; i < nb1; i += blockDim.x) if (c1[i]) atomicAdd(&bcnt1[i], c1[i]);
    for (int i = tid; i < nb2; i += blockDim.x) if (c2[i]) atomicAdd(&bcnt2[i], c2[i]);
}

// ---------- scan bucket counts (1 block, MAXNB threads) ----------
__global__ void bucket_scan_kernel(const int* __restrict__ bcnt1, const int* __restrict__ bcnt2,
                                   int* bb1, int* bb2, int* bcur1, int* bcur2,
                                   int nb1, int nb2, int E) {
    __shared__ int tmp[MAXNB];
    int t = threadIdx.x;
    int v1 = (t < nb1) ? bcnt1[t] : 0;
    tmp[t] = v1;
    __syncthreads();
    for (int off = 1; off < MAXNB; off <<= 1) {
        int x = (t >= off) ? tmp[t - off] : 0;
        __syncthreads();
        tmp[t] += x;
        __syncthreads();
    }
    if (t < nb1) { int excl = tmp[t] - v1; bb1[t] = excl; bcur1[t] = excl; }
    if (t == 0) bb1[nb1] = E;
    __syncthreads();
    int v2 = (t < nb2) ? bcnt2[t] : 0;
    tmp[t] = v2;
    __syncthreads();
    for (int off = 1; off < MAXNB; off <<= 1) {
        int x = (t >= off) ? tmp[t - off] : 0;
        __syncthreads();
        tmp[t] += x;
        __syncthreads();
    }
    if (t < nb2) { int excl = tmp[t] - v2; bb2[t] = excl; bcur2[t] = excl; }
    if (t == 0) bb2[nb2] = E;
}

// ---------- partition: emit (t, nodelocal<<25|j) records into bucket regions ----------
__global__ void partition_kernel(const int* __restrict__ seg1, const int* __restrict__ seg2,
                                 const float* __restrict__ trans, int E,
                                 int* bcur1, int* bcur2,
                                 float2* __restrict__ tmp1, float2* __restrict__ tmp2) {
    __shared__ int c1[MAXNB], c2[MAXNB];
    int tid = threadIdx.x;
    int base = blockIdx.x * PT_TILE;
    int end = base + PT_TILE;
    if (end > E) end = E;
    for (int i = tid; i < MAXNB; i += blockDim.x) { c1[i] = 0; c2[i] = 0; }
    __syncthreads();
    for (int i = base + tid; i < end; i += blockDim.x) {
        atomicAdd(&c1[seg1[i] >> BSH], 1);
        atomicAdd(&c2[seg2[i] >> BSH], 1);
    }
    __syncthreads();
    for (int i = tid; i < MAXNB; i += blockDim.x) {
        int n = c1[i]; c1[i] = n ? atomicAdd(&bcur1[i], n) : 0;
        n = c2[i];     c2[i] = n ? atomicAdd(&bcur2[i], n) : 0;
    }
    __syncthreads();
    for (int i = base + tid; i < end; i += blockDim.x) {
        int s1 = seg1[i], s2 = seg2[i];
        float t = trans[i];
        int p = atomicAdd(&c1[s1 >> BSH], 1);
        tmp1[p] = make_float2(t, __int_as_float(((s1 & (BSZ - 1)) << 25) | s2));
        int q = atomicAdd(&c2[s2 >> BSH], 1);
        tmp2[q] = make_float2(t, __int_as_float(((s2 & (BSZ - 1)) << 25) | s1));
    }
}

// ---------- bin2 (fused both sides): bucket records -> node-sorted CSR (t, j) ----------
__global__ void bin2_kernel(const float2* __restrict__ tmp1, const int* __restrict__ bb1,
                            int n1, int* __restrict__ cur1, int* __restrict__ deg1,
                            float2* __restrict__ csr1,
                            const float2* __restrict__ tmp2, const int* __restrict__ bb2,
                            int n2, int* __restrict__ cur2, int* __restrict__ deg2,
                            float2* __restrict__ csr2, int nb1) {
    __shared__ int cnt[BSZ];
    __shared__ int off[BSZ];
    __shared__ int sc[BSZ];
    int b = blockIdx.x;
    const float2* tmp; const int* bb; int n; int* cur; int* deg; float2* csr;
    if (b < nb1) { tmp = tmp1; bb = bb1; n = n1; cur = cur1; deg = deg1; csr = csr1; }
    else { b -= nb1; tmp = tmp2; bb = bb2; n = n2; cur = cur2; deg = deg2; csr = csr2; }
    int tid = threadIdx.x;
    int node0 = b << BSH;
    int s = bb[b], e_end = bb[b + 1];
    for (int i = tid; i < BSZ; i += blockDim.x) cnt[i] = 0;
    __syncthreads();
    for (int i = s + tid; i < e_end; i += blockDim.x)
        atomicAdd(&cnt[((unsigned)__float_as_int(tmp[i].y)) >> 25], 1);
    __syncthreads();
    if (tid < BSZ) sc[tid] = cnt[tid];
    __syncthreads();
    for (int o = 1; o < BSZ; o <<= 1) {
        int x = (tid >= o && tid < BSZ) ? sc[tid - o] : 0;
        __syncthreads();
        if (tid < BSZ) sc[tid] += x;
        __syncthreads();
    }
    if (tid < BSZ) {
        int excl = sc[tid] - cnt[tid] + s;
        off[tid] = excl;
        int node = node0 + tid;
        if (node < n) { cur[node] = excl; deg[node] = cnt[tid]; }
    }
    __syncthreads();
    for (int i = s + tid; i < e_end; i += blockDim.x) {
        float2 r = tmp[i];
        unsigned pay = (unsigned)__float_as_int(r.y);
        int pos = atomicAdd(&off[pay >> 25], 1);
        csr[pos] = make_float2(r.x, __int_as_float((int)(pay & 0x1FFFFFFu)));
    }
}

// ---------- gather (LDS-free): softmax + packed-broadcast bf16 V gather -> bf16 raw msg ----------
__global__ void gather_ms_kernel(int n1, int n2,
                                 const int* __restrict__ cur1, const int* __restrict__ deg1,
                                 const float2* __restrict__ csr1,
                                 const unsigned short* __restrict__ Vb2,
                                 float2* __restrict__ minv1,
                                 const int* __restrict__ cur2, const int* __restrict__ deg2,
                                 const float2* __restrict__ csr2,
                                 const unsigned short* __restrict__ Vb1,
                                 float2* __restrict__ minv2,
                                 unsigned short* __restrict__ msgr,   // (n1+n2)*64 bf16, concat rows
                                 float invT) {
    int tid = threadIdx.x;
    int wave = tid >> 6, lane = tid & 63;
    int wpb = blockDim.x >> 6;
    int g = lane >> 4, l = lane & 15;
    int total = n1 + n2;
    for (int idx = blockIdx.x * wpb + wave; idx < total; idx += gridDim.x * wpb) {
        const int *cur, *deg; const float2* csr; const unsigned short* V;
        float2* minv; int nd;
        if (idx < n1) {
            cur = cur1; deg = deg1; csr = csr1; V = Vb2; minv = minv1; nd = idx;
        } else {
            cur = cur2; deg = deg2; csr = csr2; V = Vb1; minv = minv2; nd = idx - n1;
        }
        int d = deg[nd];
        int start = cur[nd];
        float4 acc = make_float4(0.f, 0.f, 0.f, 0.f);
        if (d > 0) {
            float t0 = -INFINITY, t1 = -INFINITY, t2 = -INFINITY;
            int j0 = 0, j1 = 0, j2 = 0;
            if (lane < d)       { float2 r = csr[start + lane];       t0 = r.x; j0 = __float_as_int(r.y); }
            if (lane + 64 < d)  { float2 r = csr[start + lane + 64];  t1 = r.x; j1 = __float_as_int(r.y); }
            if (lane + 128 < d) { float2 r = csr[start + lane + 128]; t2 = r.x; j2 = __float_as_int(r.y); }
            float m = fmaxf(fmaxf(t0, t1), t2);
            for (int k = 192 + lane; k < d; k += 64) m = fmaxf(m, csr[start + k].x);
            m = fmaxf(m, __shfl_xor(m, 1));
            m = fmaxf(m, __shfl_xor(m, 2));
            m = fmaxf(m, __shfl_xor(m, 4));
            m = fmaxf(m, __shfl_xor(m, 8));
            m = fmaxf(m, __shfl_xor(m, 16));
            m = fmaxf(m, __shfl_xor(m, 32));
            float p0 = (lane < d)       ? __expf((t0 - m) * invT) : 0.f;
            float p1 = (lane + 64 < d)  ? __expf((t1 - m) * invT) : 0.f;
            float p2 = (lane + 128 < d) ? __expf((t2 - m) * invT) : 0.f;
            float s = p0 + p1 + p2;
            for (int k = 192 + lane; k < d; k += 64) s += __expf((csr[start + k].x - m) * invT);
            s += __shfl_xor(s, 1);
            s += __shfl_xor(s, 2);
            s += __shfl_xor(s, 4);
            s += __shfl_xor(s, 8);
            s += __shfl_xor(s, 16);
            s += __shfl_xor(s, 32);
            float inv = 1.f / (s + 1e-8f);
            if (lane == 0) minv[nd] = make_float2(m, inv);
            // pack (w bf16)<<16 | j16 -> one shfl per edge
            unsigned u0 = ((unsigned)f2b(p0 * inv) << 16) | (unsigned)j0;
            unsigned u1 = ((unsigned)f2b(p1 * inv) << 16) | (unsigned)j1;
            unsigned u2 = ((unsigned)f2b(p2 * inv) << 16) | (unsigned)j2;
            int c0 = d < 64 ? d : 64;
#pragma unroll 8
            for (int k = 0; k < c0; k += 4) {
                unsigned u = (unsigned)__shfl((int)u0, k + g);
                float w = bhi(u);
                int j = (int)(u & 0xFFFFu);
                uint2 v = *(const uint2*)(V + (long)j * 64 + l * 4);
                acc.x = fmaf(w, blo(v.x), acc.x);
                acc.y = fmaf(w, bhi(v.x), acc.y);
                acc.z = fmaf(w, blo(v.y), acc.z);
                acc.w = fmaf(w, bhi(v.y), acc.w);
            }
            if (d > 64) {
                int c1 = (d - 64) < 64 ? (d - 64) : 64;
#pragma unroll 8
                for (int k = 0; k < c1; k += 4) {
                    unsigned u = (unsigned)__shfl((int)u1, k + g);
                    float w = bhi(u);
                    int j = (int)(u & 0xFFFFu);
                    uint2 v = *(const uint2*)(V + (long)j * 64 + l * 4);
                    acc.x = fmaf(w, blo(v.x), acc.x);
                    acc.y = fmaf(w, bhi(v.x), acc.y);
                    acc.z = fmaf(w, blo(v.y), acc.z);
                    acc.w = fmaf(w, bhi(v.y), acc.w);
                }
            }
            if (d > 128) {
                int c2 = (d - 128) < 64 ? (d - 128) : 64;
#pragma unroll 8
                for (int k = 0; k < c2; k += 4) {
                    unsigned u = (unsigned)__shfl((int)u2, k + g);
                    float w = bhi(u);
                    int j = (int)(u & 0xFFFFu);
                    uint2 v = *(const uint2*)(V + (long)j * 64 + l * 4);
                    acc.x = fmaf(w, blo(v.x), acc.x);
                    acc.y = fmaf(w, bhi(v.x), acc.y);
                    acc.z = fmaf(w, blo(v.y), acc.z);
                    acc.w = fmaf(w, bhi(v.y), acc.w);
                }
            }
            for (int base = 192; base < d; base += 64) {
                int k = base + lane;
                unsigned ur = 0;
                if (k < d) {
                    float2 r = csr[start + k];
                    float wr = __expf((r.x - m) * invT) * inv;
                    ur = ((unsigned)f2b(wr) << 16) | (unsigned)(__float_as_int(r.y) & 0xFFFF);
                }
                int cc = (d - base) < 64 ? (d - base) : 64;
                for (int k2 = 0; k2 < cc; k2 += 4) {
                    unsigned u = (unsigned)__shfl((int)ur, k2 + g);
                    float w = bhi(u);
                    int j = (int)(u & 0xFFFFu);
                    uint2 v = *(const uint2*)(V + (long)j * 64 + l * 4);
                    acc.x = fmaf(w, blo(v.x), acc.x);
                    acc.y = fmaf(w, bhi(v.x), acc.y);
                    acc.z = fmaf(w, blo(v.y), acc.z);
                    acc.w = fmaf(w, bhi(v.y), acc.w);
                }
            }
            acc.x += __shfl_xor(acc.x, 16); acc.y += __shfl_xor(acc.y, 16);
            acc.z += __shfl_xor(acc.z, 16); acc.w += __shfl_xor(acc.w, 16);
            acc.x += __shfl_xor(acc.x, 32); acc.y += __shfl_xor(acc.y, 32);
            acc.z += __shfl_xor(acc.z, 32); acc.w += __shfl_xor(acc.w, 32);
        }
        // group 0 writes the raw row as bf16 (coalesced 8B per lane)
        if (g == 0) {
            uint2 p;
            p.x = (unsigned)f2b(acc.x) | ((unsigned)f2b(acc.y) << 16);
            p.y = (unsigned)f2b(acc.z) | ((unsigned)f2b(acc.w) << 16);
            *(uint2*)(msgr + (long)idx * 64 + l * 4) = p;
        }
    }
}

// ---------- fused tail: MFMA output projection + coalesced edge weights ----------
__global__ void tail_kernel(const unsigned short* __restrict__ msgr,
                            float* __restrict__ outp,
                            const unsigned short* __restrict__ WoT,
                            const float* __restrict__ bo, int total, int outBlocks,
                            const float* __restrict__ trans,
                            const int* __restrict__ seg1, const int* __restrict__ seg2,
                            const float2* __restrict__ minv1, const float2* __restrict__ minv2,
                            float* __restrict__ e1, float* __restrict__ e2,
                            int E, float invT) {
    if ((int)blockIdx.x < outBlocks) {
        int lane = threadIdx.x & 63;
        int wave = threadIdx.x >> 6;
        int wpb = blockDim.x >> 6;
        int ntiles = (total + 15) >> 4;
        int tile = blockIdx.x * wpb + wave;
        if (tile >= ntiles) return;
        int r0 = tile << 4;
        int rr = r0 + (lane & 15);
        if (rr > total - 1) rr = total - 1;       // tail guard (reads only)
        int kg = lane >> 4;
        int k0 = kg * 8;
        int c = lane & 15;
        const unsigned short* pr = msgr + (long)rr * 64;
        bf16x8 a0 = *(const bf16x8*)(pr + k0);
        bf16x8 a1 = *(const bf16x8*)(pr + k0 + 32);
        int orow0 = kg * 4;
#pragma unroll
        for (int n0 = 0; n0 < 64; n0 += 16) {
            bf16x8 b0 = *(const bf16x8*)(WoT + (n0 + c) * 64 + k0);
            bf16x8 b1 = *(const bf16x8*)(WoT + (n0 + c) * 64 + k0 + 32);
            f32x4 acc = {0.f, 0.f, 0.f, 0.f};
            acc = __builtin_amdgcn_mfma_f32_16x16x32_bf16(a0, b0, acc, 0, 0, 0);
            acc = __builtin_amdgcn_mfma_f32_16x16x32_bf16(a1, b1, acc, 0, 0, 0);
            float bias = bo[n0 + c];
#pragma unroll
            for (int q = 0; q < 4; ++q) {
                int r = r0 + orow0 + q;
                if (r < total) {
                    float o = acc[q] + bias;
                    o = (o >= 0.f) ? o : 0.01f * o;
                    outp[(long)r * 64 + n0 + c] = o;
                }
            }
        }
    } else {
        int e = (blockIdx.x - outBlocks) * blockDim.x + threadIdx.x;
        if (e >= E) return;
        float t = trans[e];
        float2 a = minv1[seg1[e]];
        float2 b = minv2[seg2[e]];
        e1[e] = __expf((t - a.x) * invT) * a.y;
        e2[e] = __expf((t - b.x) * invT) * b.y;
    }
}

// ---------- fallback path kernels (R2-proven, f32) ----------
__global__ void proj1_kernel(const float* __restrict__ X, int N,
                             const float* __restrict__ Wk,
                             const float* __restrict__ Wv,
                             float* __restrict__ K, float* __restrict__ V) {
    __shared__ float sWk[64 * 64];
    __shared__ float sWv[64 * 64];
    int tid = threadIdx.x;
    for (int i = tid; i < 4096; i += blockDim.x) { sWk[i] = Wk[i]; sWv[i] = Wv[i]; }
    __syncthreads();
    int wave = tid >> 6, lane = tid & 63;
    int wpb = blockDim.x >> 6;
    for (int n = blockIdx.x * wpb + wave; n < N; n += gridDim.x * wpb) {
        float x = X[n * 64 + lane];
        float ak = 0.f, av = 0.f;
#pragma unroll
        for (int k = 0; k < 64; ++k) {
            float xv = __shfl(x, k);
            ak = fmaf(xv, sWk[k * 64 + lane], ak);
            av = fmaf(xv, sWv[k * 64 + lane], av);
        }
        K[n * 64 + lane] = ak;
        V[n * 64 + lane] = av;
    }
}
__global__ void logit1_kernel(const float* __restrict__ K1, const float* __restrict__ K2,
                              const int* __restrict__ seg1, const int* __restrict__ seg2,
                              float* __restrict__ trans, int E) {
    int tid = blockIdx.x * blockDim.x + threadIdx.x;
    int e = tid >> 4, g = tid & 15;
    if (e >= E) return;
    int i1 = seg1[e], i2 = seg2[e];
    float4 a = ((const float4*)(K1 + (long)i1 * 64))[g];
    float4 b = ((const float4*)(K2 + (long)i2 * 64))[g];
    float d = a.x * b.x + a.y * b.y + a.z * b.z + a.w * b.w;
    d += __shfl_xor(d, 1);
    d += __shfl_xor(d, 2);
    d += __shfl_xor(d, 4);
    d += __shfl_xor(d, 8);
    if (g == 0) trans[e] = d;
}
__global__ void zero_deg_kernel(int* d1, int* d2, int n1, int n2) {
    int i = blockIdx.x * blockDim.x + threadIdx.x;
    if (i < n1) d1[i] = 0;
    if (i < n2) d2[i] = 0;
}
__global__ void hist_kernel(const int* __restrict__ seg1, const int* __restrict__ seg2,
                            int* deg1, int* deg2, int E) {
    int e = blockIdx.x * blockDim.x + threadIdx.x;
    if (e >= E) return;
    atomicAdd(&deg1[seg1[e]], 1);
    atomicAdd(&deg2[seg2[e]], 1);
}
__global__ void scan2_kernel(const int* __restrict__ d1, int* __restrict__ c1, int n1,
                             const int* __restrict__ d2, int* __restrict__ c2, int n2) {
    const int* deg = blockIdx.x ? d2 : d1;
    int* cur = blockIdx.x ? c2 : c1;
    int n = blockIdx.x ? n2 : n1;
    __shared__ int tmp[1024];
    __shared__ int s_carry;
    int t = threadIdx.x;
    if (t == 0) s_carry = 0;
    __syncthreads();
    for (int base = 0; base < n; base += 1024) {
        int idx = base + t;
        int v = (idx < n) ? deg[idx] : 0;
        tmp[t] = v;
        __syncthreads();
        for (int off = 1; off < 1024; off <<= 1) {
            int x = (t >= off) ? tmp[t - off] : 0;
            __syncthreads();
            tmp[t] += x;
            __syncthreads();
        }
        int excl = tmp[t] - v + s_carry;
        if (idx < n) cur[idx] = excl;
        __syncthreads();
        if (t == 0) s_carry += tmp[1023];
        __syncthreads();
    }
}
__global__ void bin_kernel(const int* __restrict__ seg1, const int* __restrict__ seg2,
                           int* cur1, int* cur2,
                           int* __restrict__ el1, int* __restrict__ el2, int E) {
    int e = blockIdx.x * blockDim.x + threadIdx.x;
    if (e >= E) return;
    int p1 = atomicAdd(&cur1[seg1[e]], 1);
    el1[p1] = e;
    int p2 = atomicAdd(&cur2[seg2[e]], 1);
    el2[p2] = e;
}
__global__ void gather_out_kernel(int N, const int* __restrict__ cur, const int* __restrict__ deg,
                                  const int* __restrict__ el, const float* __restrict__ trans,
                                  const int* __restrict__ segOther, const float* __restrict__ Vother,
                                  float* __restrict__ e_out, float* __restrict__ msg_out,
                                  const float* __restrict__ Wo, const float* __restrict__ bo,
                                  float invT) {
    __shared__ float sW[64 * 64];
    int tid = threadIdx.x;
    for (int i = tid; i < 4096; i += blockDim.x) sW[i] = Wo[i];
    __syncthreads();
    int wave = tid >> 6, lane = tid & 63;
    int wpb = blockDim.x >> 6;
    int node = blockIdx.x * wpb + wave;
    if (node >= N) return;
    int d = deg[node];
    int start = cur[node] - d;
    float acc = 0.f;
    if (d > 0) {
        float m = -INFINITY;
        for (int k = lane; k < d; k += 64) m = fmaxf(m, trans[el[start + k]]);
        m = fmaxf(m, __shfl_xor(m, 1));
        m = fmaxf(m, __shfl_xor(m, 2));
        m = fmaxf(m, __shfl_xor(m, 4));
        m = fmaxf(m, __shfl_xor(m, 8));
        m = fmaxf(m, __shfl_xor(m, 16));
        m = fmaxf(m, __shfl_xor(m, 32));
        float s = 0.f;
        for (int k = lane; k < d; k += 64) s += __expf((trans[el[start + k]] - m) * invT);
        s += __shfl_xor(s, 1);
        s += __shfl_xor(s, 2);
        s += __shfl_xor(s, 4);
        s += __shfl_xor(s, 8);
        s += __shfl_xor(s, 16);
        s += __shfl_xor(s, 32);
        float inv = 1.f / (s + 1e-8f);
        for (int base = 0; base < d; base += 64) {
            int k = base + lane;
            float w = 0.f;
            int j = 0;
            if (k < d) {
                int e = el[start + k];
                w = __expf((trans[e] - m) * invT) * inv;
                e_out[e] = w;
                j = segOther[e];
            }
            int cnt = (d - base < 64) ? (d - base) : 64;
            for (int q = 0; q < cnt; ++q) {
                float wq = __shfl(w, q);
                int jq = __shfl(j, q);
                acc = fmaf(wq, Vother[(long)jq * 64 + lane], acc);
            }
        }
    }
    float o = bo[lane];
#pragma unroll
    for (int k = 0; k < 64; ++k) {
        float xv = __shfl(acc, k);
        o = fmaf(xv, sW[k * 64 + lane], o);
    }
    o = (o >= 0.f) ? o : 0.01f * o;
    msg_out[(long)node * 64 + lane] = o;
}

extern "C" void kernel_launch(void* const* d_in, const int* in_sizes, int n_in,
                              void* d_out, int out_size, void* d_ws, size_t ws_size,
                              hipStream_t stream) {
    const float* node1 = (const float*)d_in[0];
    const int* seg1 = (const int*)d_in[1];
    const float* node2 = (const float*)d_in[3];
    const int* seg2 = (const int*)d_in[4];
    const float* Wk = (const float*)d_in[6];
    const float* Wv = (const float*)d_in[7];
    const float* Wo = (const float*)d_in[8];
    const float* bo = (const float*)d_in[9];

    int n1 = in_sizes[0] / 64;
    int n2 = in_sizes[3] / 64;
    int E = in_sizes[1];

    float* out = (float*)d_out;
    float* msg1 = out;
    float* msg2 = msg1 + (long)n1 * 64;
    float* e1 = msg2 + (long)n2 * 64;
    float* e2 = e1 + E;

    const float invT = 1.0f / sqrtf(64.0f);
    int nb1 = (n1 + BSZ - 1) >> BSH;
    int nb2 = (n2 + BSZ - 1) >> BSH;
    long Epad = (E + 1) & ~1L;

    // ---- fast-path layout (weights first for 16B alignment; bf16 K/V/msg) ----
    float* ws = (float*)d_ws;
    unsigned short* WkT = (unsigned short*)ws;          // 4096 ushort
    unsigned short* WvT = WkT + 4096;                   // 4096
    unsigned short* WoT = WvT + 4096;                   // 4096
    float2* csr1 = (float2*)(ws + 6144);                // E records
    float2* csr2 = csr1 + E;                            // E
    float2* tmp1 = csr2 + E;                            // E
    float2* tmp2 = tmp1 + E;                            // E
    float* trans = (float*)(tmp2 + E);                  // Epad
    float2* minv1 = (float2*)(trans + Epad);            // n1
    float2* minv2 = minv1 + n1;                         // n2
    unsigned short* Kb1 = (unsigned short*)(minv2 + n2);// n1*64 ushort
    unsigned short* Kb2 = Kb1 + (long)n1 * 64;          // n2*64
    unsigned short* Vb1 = Kb2 + (long)n2 * 64;          // n1*64
    unsigned short* Vb2 = Vb1 + (long)n1 * 64;          // n2*64
    unsigned short* msgr = Vb2 + (long)n2 * 64;         // (n1+n2)*64 ushort
    int* deg1 = (int*)(msgr + (long)(n1 + n2) * 64);    // n1
    int* deg2 = deg1 + n1;                              // n2
    int* cur1 = deg2 + n2;                              // n1
    int* cur2 = cur1 + n1;                              // n2
    int* bb1 = cur2 + n2;                               // nb1+1
    int* bb2 = bb1 + nb1 + 1;                           // nb2+1
    int* bcur1 = bb2 + nb2 + 1;                         // nb1
    int* bcur2 = bcur1 + nb1;                           // nb2
    int* bcnt1 = bcur2 + nb2;                           // nb1
    int* bcnt2 = bcnt1 + nb1;                           // nb2
    long fp_words = 6144 + 8L * E + Epad + 2L * (n1 + n2)
                  + 64L * (n1 + n2)                     // bf16 K,V both sides
                  + 32L * (n1 + n2)                     // bf16 raw msg
                  + 2L * (n1 + n2)                      // deg, cur
                  + 3L * (nb1 + nb2) + 2;
    bool fast = (E <= (1 << 20)) && (nb1 <= MAXNB) && (nb2 <= MAXNB)
             && (n1 < 65536) && (n2 < 65536) && (n1 + n2 > 0)
             && ((size_t)fp_words * 4 <= ws_size);

    if (fast) {
        int total = n1 + n2;
        int ntiles = (total + 15) / 16;
        int gg = (total + 3) / 4;
        if (gg > 2048) gg = 2048;
        prep_kernel<<<1, 256, 0, stream>>>(Wk, Wv, Wo, WkT, WvT, WoT,
                                           bcnt1, bcnt2, nb1, nb2);
        proj_mfma_kernel<<<(ntiles + 3) / 4, 256, 0, stream>>>(
            node1, n1, node2, n2, WkT, WvT, Kb1, Vb1);
        {
            long threads = (long)E * 8;
            int blocks = (int)((threads + 255) / 256);
            logit_kernel<<<blocks, 256, 0, stream>>>(Kb1, Kb2, seg1, seg2, trans, E);
        }
        bucket_count_kernel<<<512, 256, 0, stream>>>(seg1, seg2, E, bcnt1, bcnt2, nb1, nb2);
        bucket_scan_kernel<<<1, MAXNB, 0, stream>>>(bcnt1, bcnt2, bb1, bb2, bcur1, bcur2,
                                                    nb1, nb2, E);
        partition_kernel<<<(E + PT_TILE - 1) / PT_TILE, 256, 0, stream>>>(
            seg1, seg2, trans, E, bcur1, bcur2, tmp1, tmp2);
        bin2_kernel<<<nb1 + nb2, 256, 0, stream>>>(tmp1, bb1, n1, cur1, deg1, csr1,
                                                   tmp2, bb2, n2, cur2, deg2, csr2, nb1);
        gather_ms_kernel<<<gg, 256, 0, stream>>>(
            n1, n2, cur1, deg1, csr1, Vb2, minv1,
            cur2, deg2, csr2, Vb1, minv2, msgr, invT);
        {
            int outBlocks = (ntiles + 3) / 4;
            int edgeBlocks = (E + 255) / 256;
            tail_kernel<<<outBlocks + edgeBlocks, 256, 0, stream>>>(
                msgr, msg1, WoT, bo, total, outBlocks,
                trans, seg1, seg2, minv1, minv2, e1, e2, E, invT);
        }
    } else {
        // fallback: R2-proven f32 path
        float* K1f = ws;
        float* V1f = K1f + (long)n1 * 64;
        float* K2f = V1f + (long)n1 * 64;
        float* V2f = K2f + (long)n2 * 64;
        float* transf = V2f + (long)n2 * 64;
        int* deg1f = (int*)(transf + E);
        int* deg2f = deg1f + n1;
        int* cur1f = deg2f + n2;
        int* cur2f = cur1f + n1;
        int* el1 = (int*)K1f;
        int* el2 = (int*)K2f;

        proj1_kernel<<<(n1 + 3) / 4, 256, 0, stream>>>(node1, n1, Wk, Wv, K1f, V1f);
        proj1_kernel<<<(n2 + 3) / 4, 256, 0, stream>>>(node2, n2, Wk, Wv, K2f, V2f);
        {
            long threads = (long)E * 16;
            int blocks = (int)((threads + 255) / 256);
            logit1_kernel<<<blocks, 256, 0, stream>>>(K1f, K2f, seg1, seg2, transf, E);
        }
        zero_deg_kernel<<<((n1 > n2 ? n1 : n2) + 255) / 256, 256, 0, stream>>>(deg1f, deg2f, n1, n2);
        hist_kernel<<<(E + 255) / 256, 256, 0, stream>>>(seg1, seg2, deg1f, deg2f, E);
        scan2_kernel<<<2, 1024, 0, stream>>>(deg1f, cur1f, n1, deg2f, cur2f, n2);
        bin_kernel<<<(E + 255) / 256, 256, 0, stream>>>(seg1, seg2, cur1f, cur2f, el1, el2, E);

        gather_out_kernel<<<(n1 + 3) / 4, 256, 0, stream>>>(
            n1, cur1f, deg1f, el1, transf, seg2, V2f, e1, msg1, Wo, bo, invT);
        gather_out_kernel<<<(n2 + 3) / 4, 256, 0, stream>>>(
            n2, cur2f, deg2f, el2, transf, seg1, V1f, e2, msg2, Wo, bo, invT);
    }
}

// Round 15
// 171.359 us; speedup vs baseline: 1.1754x; 1.0076x over previous
//
#include <hip/hip_runtime.h>
#include <math.h>

#define BSH 7              // 128 nodes per bucket
#define BSZ (1 << BSH)
#define MAXNB 256          // max buckets per side
#define PT_TILE 2048       // edges per partition block (R15: 4096->2048, ~2 blocks/CU)

typedef __attribute__((ext_vector_type(4))) float f32x4;
typedef __attribute__((ext_vector_type(8))) short bf16x8;

// f32 -> bf16 (round to nearest even)
__device__ __forceinline__ unsigned short f2b(float f) {
    unsigned u = __float_as_uint(f);
    return (unsigned short)((u + 0x7FFFu + ((u >> 16) & 1u)) >> 16);
}
__device__ __forceinline__ float blo(unsigned u) { return __uint_as_float(u << 16); }
__device__ __forceinline__ float bhi(unsigned u) { return __uint_as_float(u & 0xFFFF0000u); }

// ---------- prep: zero bucket counters + transposed bf16 weights ----------
__global__ void prep_kernel(const float* __restrict__ Wk, const float* __restrict__ Wv,
                            const float* __restrict__ Wo,
                            unsigned short* __restrict__ WkT, unsigned short* __restrict__ WvT,
                            unsigned short* __restrict__ WoT,
                            int* bcnt1, int* bcnt2, int nb1, int nb2) {
    int tid = threadIdx.x;
    for (int i = tid; i < nb1; i += blockDim.x) bcnt1[i] = 0;
    for (int i = tid; i < nb2; i += blockDim.x) bcnt2[i] = 0;
    for (int i = tid; i < 4096; i += blockDim.x) {
        int k = i >> 6, c = i & 63;
        WkT[c * 64 + k] = f2b(Wk[i]);
        WvT[c * 64 + k] = f2b(Wv[i]);
        WoT[c * 64 + k] = f2b(Wo[i]);
    }
}

// ---------- fused: MFMA projections (blocks < projBlocks) + bucket histogram (rest) ----------
// proj: A frag row = lane&15, k-slot (lane>>4, t); B frag col = lane&15, same k-slot map.
// D frag: col = lane&15, row = (lane>>4)*4 + reg   [m89, verified in-harness R11/R12]
__global__ void proj_count_kernel(const float* __restrict__ X1, int n1,
                                  const float* __restrict__ X2, int n2,
                                  const unsigned short* __restrict__ WkT,
                                  const unsigned short* __restrict__ WvT,
                                  unsigned short* __restrict__ Kall,
                                  unsigned short* __restrict__ Vall,
                                  int projBlocks,
                                  const int* __restrict__ seg1, const int* __restrict__ seg2,
                                  int E, int* bcnt1, int* bcnt2, int nb1, int nb2) {
    __shared__ int c1[MAXNB], c2[MAXNB];
    int total = n1 + n2;
    if ((int)blockIdx.x < projBlocks) {
        int lane = threadIdx.x & 63;
        int wave = threadIdx.x >> 6;
        int wpb = blockDim.x >> 6;
        int ntiles = (total + 15) >> 4;
        int tile = blockIdx.x * wpb + wave;
        if (tile >= ntiles) return;
        int r0 = tile << 4;
        int rr = r0 + (lane & 15);
        if (rr > total - 1) rr = total - 1;      // tail guard (reads only)
        int kg = lane >> 4;
        int k0 = kg * 8;
        int c = lane & 15;
        const float* xp = (rr < n1) ? (X1 + (long)rr * 64) : (X2 + (long)(rr - n1) * 64);
        float4 xa = *(const float4*)(xp + k0);
        float4 xb = *(const float4*)(xp + k0 + 4);
        float4 xc = *(const float4*)(xp + k0 + 32);
        float4 xd = *(const float4*)(xp + k0 + 36);
        bf16x8 a0, a1;
        a0[0] = (short)f2b(xa.x); a0[1] = (short)f2b(xa.y);
        a0[2] = (short)f2b(xa.z); a0[3] = (short)f2b(xa.w);
        a0[4] = (short)f2b(xb.x); a0[5] = (short)f2b(xb.y);
        a0[6] = (short)f2b(xb.z); a0[7] = (short)f2b(xb.w);
        a1[0] = (short)f2b(xc.x); a1[1] = (short)f2b(xc.y);
        a1[2] = (short)f2b(xc.z); a1[3] = (short)f2b(xc.w);
        a1[4] = (short)f2b(xd.x); a1[5] = (short)f2b(xd.y);
        a1[6] = (short)f2b(xd.z); a1[7] = (short)f2b(xd.w);
        int orow0 = kg * 4;
#pragma unroll
        for (int n0 = 0; n0 < 64; n0 += 16) {
            bf16x8 bk0 = *(const bf16x8*)(WkT + (n0 + c) * 64 + k0);
            bf16x8 bk1 = *(const bf16x8*)(WkT + (n0 + c) * 64 + k0 + 32);
            bf16x8 bv0 = *(const bf16x8*)(WvT + (n0 + c) * 64 + k0);
            bf16x8 bv1 = *(const bf16x8*)(WvT + (n0 + c) * 64 + k0 + 32);
            f32x4 aK = {0.f, 0.f, 0.f, 0.f};
            f32x4 aV = {0.f, 0.f, 0.f, 0.f};
            aK = __builtin_amdgcn_mfma_f32_16x16x32_bf16(a0, bk0, aK, 0, 0, 0);
            aK = __builtin_amdgcn_mfma_f32_16x16x32_bf16(a1, bk1, aK, 0, 0, 0);
            aV = __builtin_amdgcn_mfma_f32_16x16x32_bf16(a0, bv0, aV, 0, 0, 0);
            aV = __builtin_amdgcn_mfma_f32_16x16x32_bf16(a1, bv1, aV, 0, 0, 0);
#pragma unroll
            for (int q = 0; q < 4; ++q) {
                int r = r0 + orow0 + q;
                if (r < total) {
                    Kall[(long)r * 64 + n0 + c] = f2b(aK[q]);
                    Vall[(long)r * 64 + n0 + c] = f2b(aV[q]);
                }
            }
        }
    } else {
        // bucket histogram (seg-only; depends only on prep's bcnt zeroing)
        int tid = threadIdx.x;
        int cb = blockIdx.x - projBlocks;
        int ncb = gridDim.x - projBlocks;
        for (int i = tid; i < MAXNB; i += blockDim.x) { c1[i] = 0; c2[i] = 0; }
        __syncthreads();
        for (int i = cb * blockDim.x + tid; i < E; i += ncb * blockDim.x) {
            atomicAdd(&c1[seg1[i] >> BSH], 1);
            atomicAdd(&c2[seg2[i] >> BSH], 1);
        }
        __syncthreads();
        for (int i = tid; i < nb1; i += blockDim.x) if (c1[i]) atomicAdd(&bcnt1[i], c1[i]);
        for (int i = tid; i < nb2; i += blockDim.x) if (c2[i]) atomicAdd(&bcnt2[i], c2[i]);
    }
}

// ---------- edge logits (bf16 K rows, 8 lanes/edge, 16B loads) ----------
__global__ void logit_kernel(const unsigned short* __restrict__ K1,
                             const unsigned short* __restrict__ K2,
                             const int* __restrict__ seg1, const int* __restrict__ seg2,
                             float* __restrict__ trans, int E) {
    int tid = blockIdx.x * blockDim.x + threadIdx.x;
    int e = tid >> 3, g = tid & 7;
    if (e >= E) return;
    int i1 = seg1[e], i2 = seg2[e];
    uint4 a = *(const uint4*)(K1 + (long)i1 * 64 + g * 8);
    uint4 b = *(const uint4*)(K2 + (long)i2 * 64 + g * 8);
    float d = blo(a.x) * blo(b.x);
    d = fmaf(bhi(a.x), bhi(b.x), d);
    d = fmaf(blo(a.y), blo(b.y), d);
    d = fmaf(bhi(a.y), bhi(b.y), d);
    d = fmaf(blo(a.z), blo(b.z), d);
    d = fmaf(bhi(a.z), bhi(b.z), d);
    d = fmaf(blo(a.w), blo(b.w), d);
    d = fmaf(bhi(a.w), bhi(b.w), d);
    d += __shfl_xor(d, 1);
    d += __shfl_xor(d, 2);
    d += __shfl_xor(d, 4);
    if (g == 0) trans[e] = d;
}

// ---------- scan bucket counts (1 block, MAXNB threads) ----------
__global__ void bucket_scan_kernel(const int* __restrict__ bcnt1, const int* __restrict__ bcnt2,
                                   int* bb1, int* bb2, int* bcur1, int* bcur2,
                                   int nb1, int nb2, int E) {
    __shared__ int tmp[MAXNB];
    int t = threadIdx.x;
    int v1 = (t < nb1) ? bcnt1[t] : 0;
    tmp[t] = v1;
    __syncthreads();
    for (int off = 1; off < MAXNB; off <<= 1) {
        int x = (t >= off) ? tmp[t - off] : 0;
        __syncthreads();
        tmp[t] += x;
        __syncthreads();
    }
    if (t < nb1) { int excl = tmp[t] - v1; bb1[t] = excl; bcur1[t] = excl; }
    if (t == 0) bb1[nb1] = E;
    __syncthreads();
    int v2 = (t < nb2) ? bcnt2[t] : 0;
    tmp[t] = v2;
    __syncthreads();
    for (int off = 1; off < MAXNB; off <<= 1) {
        int x = (t >= off) ? tmp[t - off] : 0;
        __syncthreads();
        tmp[t] += x;
        __syncthreads();
    }
    if (t < nb2) { int excl = tmp[t] - v2; bb2[t] = excl; bcur2[t] = excl; }
    if (t == 0) bb2[nb2] = E;
}

// ---------- partition: emit (t, nodelocal<<25|j) records into bucket regions ----------
__global__ void partition_kernel(const int* __restrict__ seg1, const int* __restrict__ seg2,
                                 const float* __restrict__ trans, int E,
                                 int* bcur1, int* bcur2,
                                 float2* __restrict__ tmp1, float2* __restrict__ tmp2) {
    __shared__ int c1[MAXNB], c2[MAXNB];
    int tid = threadIdx.x;
    int base = blockIdx.x * PT_TILE;
    int end = base + PT_TILE;
    if (end > E) end = E;
    for (int i = tid; i < MAXNB; i += blockDim.x) { c1[i] = 0; c2[i] = 0; }
    __syncthreads();
    for (int i = base + tid; i < end; i += blockDim.x) {
        atomicAdd(&c1[seg1[i] >> BSH], 1);
        atomicAdd(&c2[seg2[i] >> BSH], 1);
    }
    __syncthreads();
    for (int i = tid; i < MAXNB; i += blockDim.x) {
        int n = c1[i]; c1[i] = n ? atomicAdd(&bcur1[i], n) : 0;
        n = c2[i];     c2[i] = n ? atomicAdd(&bcur2[i], n) : 0;
    }
    __syncthreads();
    for (int i = base + tid; i < end; i += blockDim.x) {
        int s1 = seg1[i], s2 = seg2[i];
        float t = trans[i];
        int p = atomicAdd(&c1[s1 >> BSH], 1);
        tmp1[p] = make_float2(t, __int_as_float(((s1 & (BSZ - 1)) << 25) | s2));
        int q = atomicAdd(&c2[s2 >> BSH], 1);
        tmp2[q] = make_float2(t, __int_as_float(((s2 & (BSZ - 1)) << 25) | s1));
    }
}

// ---------- bin2 (fused both sides): bucket records -> node-sorted CSR (t, j) ----------
__global__ void bin2_kernel(const float2* __restrict__ tmp1, const int* __restrict__ bb1,
                            int n1, int* __restrict__ cur1, int* __restrict__ deg1,
                            float2* __restrict__ csr1,
                            const float2* __restrict__ tmp2, const int* __restrict__ bb2,
                            int n2, int* __restrict__ cur2, int* __restrict__ deg2,
                            float2* __restrict__ csr2, int nb1) {
    __shared__ int cnt[BSZ];
    __shared__ int off[BSZ];
    __shared__ int sc[BSZ];
    int b = blockIdx.x;
    const float2* tmp; const int* bb; int n; int* cur; int* deg; float2* csr;
    if (b < nb1) { tmp = tmp1; bb = bb1; n = n1; cur = cur1; deg = deg1; csr = csr1; }
    else { b -= nb1; tmp = tmp2; bb = bb2; n = n2; cur = cur2; deg = deg2; csr = csr2; }
    int tid = threadIdx.x;
    int node0 = b << BSH;
    int s = bb[b], e_end = bb[b + 1];
    for (int i = tid; i < BSZ; i += blockDim.x) cnt[i] = 0;
    __syncthreads();
    for (int i = s + tid; i < e_end; i += blockDim.x)
        atomicAdd(&cnt[((unsigned)__float_as_int(tmp[i].y)) >> 25], 1);
    __syncthreads();
    if (tid < BSZ) sc[tid] = cnt[tid];
    __syncthreads();
    for (int o = 1; o < BSZ; o <<= 1) {
        int x = (tid >= o && tid < BSZ) ? sc[tid - o] : 0;
        __syncthreads();
        if (tid < BSZ) sc[tid] += x;
        __syncthreads();
    }
    if (tid < BSZ) {
        int excl = sc[tid] - cnt[tid] + s;
        off[tid] = excl;
        int node = node0 + tid;
        if (node < n) { cur[node] = excl; deg[node] = cnt[tid]; }
    }
    __syncthreads();
    for (int i = s + tid; i < e_end; i += blockDim.x) {
        float2 r = tmp[i];
        unsigned pay = (unsigned)__float_as_int(r.y);
        int pos = atomicAdd(&off[pay >> 25], 1);
        csr[pos] = make_float2(r.x, __int_as_float((int)(pay & 0x1FFFFFFu)));
    }
}

// ---------- gather (LDS-free, one-shot grid): softmax + packed bf16 V gather -> bf16 msg ----------
__global__ void gather_ms_kernel(int n1, int n2,
                                 const int* __restrict__ cur1, const int* __restrict__ deg1,
                                 const float2* __restrict__ csr1,
                                 const unsigned short* __restrict__ Vb2,
                                 float2* __restrict__ minv1,
                                 const int* __restrict__ cur2, const int* __restrict__ deg2,
                                 const float2* __restrict__ csr2,
                                 const unsigned short* __restrict__ Vb1,
                                 float2* __restrict__ minv2,
                                 unsigned short* __restrict__ msgr,   // (n1+n2)*64 bf16, concat rows
                                 float invT) {
    int tid = threadIdx.x;
    int wave = tid >> 6, lane = tid & 63;
    int wpb = blockDim.x >> 6;
    int g = lane >> 4, l = lane & 15;
    int total = n1 + n2;
    int idx = blockIdx.x * wpb + wave;
    if (idx >= total) return;
    {
        const int *cur, *deg; const float2* csr; const unsigned short* V;
        float2* minv; int nd;
        if (idx < n1) {
            cur = cur1; deg = deg1; csr = csr1; V = Vb2; minv = minv1; nd = idx;
        } else {
            cur = cur2; deg = deg2; csr = csr2; V = Vb1; minv = minv2; nd = idx - n1;
        }
        int d = deg[nd];
        int start = cur[nd];
        float4 acc = make_float4(0.f, 0.f, 0.f, 0.f);
        if (d > 0) {
            float t0 = -INFINITY, t1 = -INFINITY, t2 = -INFINITY;
            int j0 = 0, j1 = 0, j2 = 0;
            if (lane < d)       { float2 r = csr[start + lane];       t0 = r.x; j0 = __float_as_int(r.y); }
            if (lane + 64 < d)  { float2 r = csr[start + lane + 64];  t1 = r.x; j1 = __float_as_int(r.y); }
            if (lane + 128 < d) { float2 r = csr[start + lane + 128]; t2 = r.x; j2 = __float_as_int(r.y); }
            float m = fmaxf(fmaxf(t0, t1), t2);
            for (int k = 192 + lane; k < d; k += 64) m = fmaxf(m, csr[start + k].x);
            m = fmaxf(m, __shfl_xor(m, 1));
            m = fmaxf(m, __shfl_xor(m, 2));
            m = fmaxf(m, __shfl_xor(m, 4));
            m = fmaxf(m, __shfl_xor(m, 8));
            m = fmaxf(m, __shfl_xor(m, 16));
            m = fmaxf(m, __shfl_xor(m, 32));
            float p0 = (lane < d)       ? __expf((t0 - m) * invT) : 0.f;
            float p1 = (lane + 64 < d)  ? __expf((t1 - m) * invT) : 0.f;
            float p2 = (lane + 128 < d) ? __expf((t2 - m) * invT) : 0.f;
            float s = p0 + p1 + p2;
            for (int k = 192 + lane; k < d; k += 64) s += __expf((csr[start + k].x - m) * invT);
            s += __shfl_xor(s, 1);
            s += __shfl_xor(s, 2);
            s += __shfl_xor(s, 4);
            s += __shfl_xor(s, 8);
            s += __shfl_xor(s, 16);
            s += __shfl_xor(s, 32);
            float inv = 1.f / (s + 1e-8f);
            if (lane == 0) minv[nd] = make_float2(m, inv);
            // pack (w bf16)<<16 | j16 -> one shfl per edge
            unsigned u0 = ((unsigned)f2b(p0 * inv) << 16) | (unsigned)j0;
            unsigned u1 = ((unsigned)f2b(p1 * inv) << 16) | (unsigned)j1;
            unsigned u2 = ((unsigned)f2b(p2 * inv) << 16) | (unsigned)j2;
            int c0 = d < 64 ? d : 64;
#pragma unroll 8
            for (int k = 0; k < c0; k += 4) {
                unsigned u = (unsigned)__shfl((int)u0, k + g);
                float w = bhi(u);
                int j = (int)(u & 0xFFFFu);
                uint2 v = *(const uint2*)(V + (long)j * 64 + l * 4);
                acc.x = fmaf(w, blo(v.x), acc.x);
                acc.y = fmaf(w, bhi(v.x), acc.y);
                acc.z = fmaf(w, blo(v.y), acc.z);
                acc.w = fmaf(w, bhi(v.y), acc.w);
            }
            if (d > 64) {
                int c1 = (d - 64) < 64 ? (d - 64) : 64;
#pragma unroll 8
                for (int k = 0; k < c1; k += 4) {
                    unsigned u = (unsigned)__shfl((int)u1, k + g);
                    float w = bhi(u);
                    int j = (int)(u & 0xFFFFu);
                    uint2 v = *(const uint2*)(V + (long)j * 64 + l * 4);
                    acc.x = fmaf(w, blo(v.x), acc.x);
                    acc.y = fmaf(w, bhi(v.x), acc.y);
                    acc.z = fmaf(w, blo(v.y), acc.z);
                    acc.w = fmaf(w, bhi(v.y), acc.w);
                }
            }
            if (d > 128) {
                int c2 = (d - 128) < 64 ? (d - 128) : 64;
#pragma unroll 8
                for (int k = 0; k < c2; k += 4) {
                    unsigned u = (unsigned)__shfl((int)u2, k + g);
                    float w = bhi(u);
                    int j = (int)(u & 0xFFFFu);
                    uint2 v = *(const uint2*)(V + (long)j * 64 + l * 4);
                    acc.x = fmaf(w, blo(v.x), acc.x);
                    acc.y = fmaf(w, bhi(v.x), acc.y);
                    acc.z = fmaf(w, blo(v.y), acc.z);
                    acc.w = fmaf(w, bhi(v.y), acc.w);
                }
            }
            for (int base = 192; base < d; base += 64) {
                int k = base + lane;
                unsigned ur = 0;
                if (k < d) {
                    float2 r = csr[start + k];
                    float wr = __expf((r.x - m) * invT) * inv;
                    ur = ((unsigned)f2b(wr) << 16) | (unsigned)(__float_as_int(r.y) & 0xFFFF);
                }
                int cc = (d - base) < 64 ? (d - base) : 64;
                for (int k2 = 0; k2 < cc; k2 += 4) {
                    unsigned u = (unsigned)__shfl((int)ur, k2 + g);
                    float w = bhi(u);
                    int j = (int)(u & 0xFFFFu);
                    uint2 v = *(const uint2*)(V + (long)j * 64 + l * 4);
                    acc.x = fmaf(w, blo(v.x), acc.x);
                    acc.y = fmaf(w, bhi(v.x), acc.y);
                    acc.z = fmaf(w, blo(v.y), acc.z);
                    acc.w = fmaf(w, bhi(v.y), acc.w);
                }
            }
            acc.x += __shfl_xor(acc.x, 16); acc.y += __shfl_xor(acc.y, 16);
            acc.z += __shfl_xor(acc.z, 16); acc.w += __shfl_xor(acc.w, 16);
            acc.x += __shfl_xor(acc.x, 32); acc.y += __shfl_xor(acc.y, 32);
            acc.z += __shfl_xor(acc.z, 32); acc.w += __shfl_xor(acc.w, 32);
        }
        // group 0 writes the raw row as bf16 (coalesced 8B per lane)
        if (g == 0) {
            uint2 p;
            p.x = (unsigned)f2b(acc.x) | ((unsigned)f2b(acc.y) << 16);
            p.y = (unsigned)f2b(acc.z) | ((unsigned)f2b(acc.w) << 16);
            *(uint2*)(msgr + (long)idx * 64 + l * 4) = p;
        }
    }
}

// ---------- fused tail: MFMA output projection + coalesced edge weights ----------
__global__ void tail_kernel(const unsigned short* __restrict__ msgr,
                            float* __restrict__ outp,
                            const unsigned short* __restrict__ WoT,
                            const float* __restrict__ bo, int total, int outBlocks,
                            const float* __restrict__ trans,
                            const int* __restrict__ seg1, const int* __restrict__ seg2,
                            const float2* __restrict__ minv1, const float2* __restrict__ minv2,
                            float* __restrict__ e1, float* __restrict__ e2,
                            int E, float invT) {
    if ((int)blockIdx.x < outBlocks) {
        int lane = threadIdx.x & 63;
        int wave = threadIdx.x >> 6;
        int wpb = blockDim.x >> 6;
        int ntiles = (total + 15) >> 4;
        int tile = blockIdx.x * wpb + wave;
        if (tile >= ntiles) return;
        int r0 = tile << 4;
        int rr = r0 + (lane & 15);
        if (rr > total - 1) rr = total - 1;       // tail guard (reads only)
        int kg = lane >> 4;
        int k0 = kg * 8;
        int c = lane & 15;
        const unsigned short* pr = msgr + (long)rr * 64;
        bf16x8 a0 = *(const bf16x8*)(pr + k0);
        bf16x8 a1 = *(const bf16x8*)(pr + k0 + 32);
        int orow0 = kg * 4;
#pragma unroll
        for (int n0 = 0; n0 < 64; n0 += 16) {
            bf16x8 b0 = *(const bf16x8*)(WoT + (n0 + c) * 64 + k0);
            bf16x8 b1 = *(const bf16x8*)(WoT + (n0 + c) * 64 + k0 + 32);
            f32x4 acc = {0.f, 0.f, 0.f, 0.f};
            acc = __builtin_amdgcn_mfma_f32_16x16x32_bf16(a0, b0, acc, 0, 0, 0);
            acc = __builtin_amdgcn_mfma_f32_16x16x32_bf16(a1, b1, acc, 0, 0, 0);
            float bias = bo[n0 + c];
#pragma unroll
            for (int q = 0; q < 4; ++q) {
                int r = r0 + orow0 + q;
                if (r < total) {
                    float o = acc[q] + bias;
                    o = (o >= 0.f) ? o : 0.01f * o;
                    outp[(long)r * 64 + n0 + c] = o;
                }
            }
        }
    } else {
        int e = (blockIdx.x - outBlocks) * blockDim.x + threadIdx.x;
        if (e >= E) return;
        float t = trans[e];
        float2 a = minv1[seg1[e]];
        float2 b = minv2[seg2[e]];
        e1[e] = __expf((t - a.x) * invT) * a.y;
        e2[e] = __expf((t - b.x) * invT) * b.y;
    }
}

// ---------- fallback path kernels (R2-proven, f32) ----------
__global__ void proj1_kernel(const float* __restrict__ X, int N,
                             const float* __restrict__ Wk,
                             const float* __restrict__ Wv,
                             float* __restrict__ K, float* __restrict__ V) {
    __shared__ float sWk[64 * 64];
    __shared__ float sWv[64 * 64];
    int tid = threadIdx.x;
    for (int i = tid; i < 4096; i += blockDim.x) { sWk[i] = Wk[i]; sWv[i] = Wv[i]; }
    __syncthreads();
    int wave = tid >> 6, lane = tid & 63;
    int wpb = blockDim.x >> 6;
    for (int n = blockIdx.x * wpb + wave; n < N; n += gridDim.x * wpb) {
        float x = X[n * 64 + lane];
        float ak = 0.f, av = 0.f;
#pragma unroll
        for (int k = 0; k < 64; ++k) {
            float xv = __shfl(x, k);
            ak = fmaf(xv, sWk[k * 64 + lane], ak);
            av = fmaf(xv, sWv[k * 64 + lane], av);
        }
        K[n * 64 + lane] = ak;
        V[n * 64 + lane] = av;
    }
}
__global__ void logit1_kernel(const float* __restrict__ K1, const float* __restrict__ K2,
                              const int* __restrict__ seg1, const int* __restrict__ seg2,
                              float* __restrict__ trans, int E) {
    int tid = blockIdx.x * blockDim.x + threadIdx.x;
    int e = tid >> 4, g = tid & 15;
    if (e >= E) return;
    int i1 = seg1[e], i2 = seg2[e];
    float4 a = ((const float4*)(K1 + (long)i1 * 64))[g];
    float4 b = ((const float4*)(K2 + (long)i2 * 64))[g];
    float d = a.x * b.x + a.y * b.y + a.z * b.z + a.w * b.w;
    d += __shfl_xor(d, 1);
    d += __shfl_xor(d, 2);
    d += __shfl_xor(d, 4);
    d += __shfl_xor(d, 8);
    if (g == 0) trans[e] = d;
}
__global__ void zero_deg_kernel(int* d1, int* d2, int n1, int n2) {
    int i = blockIdx.x * blockDim.x + threadIdx.x;
    if (i < n1) d1[i] = 0;
    if (i < n2) d2[i] = 0;
}
__global__ void hist_kernel(const int* __restrict__ seg1, const int* __restrict__ seg2,
                            int* deg1, int* deg2, int E) {
    int e = blockIdx.x * blockDim.x + threadIdx.x;
    if (e >= E) return;
    atomicAdd(&deg1[seg1[e]], 1);
    atomicAdd(&deg2[seg2[e]], 1);
}
__global__ void scan2_kernel(const int* __restrict__ d1, int* __restrict__ c1, int n1,
                             const int* __restrict__ d2, int* __restrict__ c2, int n2) {
    const int* deg = blockIdx.x ? d2 : d1;
    int* cur = blockIdx.x ? c2 : c1;
    int n = blockIdx.x ? n2 : n1;
    __shared__ int tmp[1024];
    __shared__ int s_carry;
    int t = threadIdx.x;
    if (t == 0) s_carry = 0;
    __syncthreads();
    for (int base = 0; base < n; base += 1024) {
        int idx = base + t;
        int v = (idx < n) ? deg[idx] : 0;
        tmp[t] = v;
        __syncthreads();
        for (int off = 1; off < 1024; off <<= 1) {
            int x = (t >= off) ? tmp[t - off] : 0;
            __syncthreads();
            tmp[t] += x;
            __syncthreads();
        }
        int excl = tmp[t] - v + s_carry;
        if (idx < n) cur[idx] = excl;
        __syncthreads();
        if (t == 0) s_carry += tmp[1023];
        __syncthreads();
    }
}
__global__ void bin_kernel(const int* __restrict__ seg1, const int* __restrict__ seg2,
                           int* cur1, int* cur2,
                           int* __restrict__ el1, int* __restrict__ el2, int E) {
    int e = blockIdx.x * blockDim.x + threadIdx.x;
    if (e >= E) return;
    int p1 = atomicAdd(&cur1[seg1[e]], 1);
    el1[p1] = e;
    int p2 = atomicAdd(&cur2[seg2[e]], 1);
    el2[p2] = e;
}
__global__ void gather_out_kernel(int N, const int* __restrict__ cur, const int* __restrict__ deg,
                                  const int* __restrict__ el, const float* __restrict__ trans,
                                  const int* __restrict__ segOther, const float* __restrict__ Vother,
                                  float* __restrict__ e_out, float* __restrict__ msg_out,
                                  const float* __restrict__ Wo, const float* __restrict__ bo,
                                  float invT) {
    __shared__ float sW[64 * 64];
    int tid = threadIdx.x;
    for (int i = tid; i < 4096; i += blockDim.x) sW[i] = Wo[i];
    __syncthreads();
    int wave = tid >> 6, lane = tid & 63;
    int wpb = blockDim.x >> 6;
    int node = blockIdx.x * wpb + wave;
    if (node >= N) return;
    int d = deg[node];
    int start = cur[node] - d;
    float acc = 0.f;
    if (d > 0) {
        float m = -INFINITY;
        for (int k = lane; k < d; k += 64) m = fmaxf(m, trans[el[start + k]]);
        m = fmaxf(m, __shfl_xor(m, 1));
        m = fmaxf(m, __shfl_xor(m, 2));
        m = fmaxf(m, __shfl_xor(m, 4));
        m = fmaxf(m, __shfl_xor(m, 8));
        m = fmaxf(m, __shfl_xor(m, 16));
        m = fmaxf(m, __shfl_xor(m, 32));
        float s = 0.f;
        for (int k = lane; k < d; k += 64) s += __expf((trans[el[start + k]] - m) * invT);
        s += __shfl_xor(s, 1);
        s += __shfl_xor(s, 2);
        s += __shfl_xor(s, 4);
        s += __shfl_xor(s, 8);
        s += __shfl_xor(s, 16);
        s += __shfl_xor(s, 32);
        float inv = 1.f / (s + 1e-8f);
        for (int base = 0; base < d; base += 64) {
            int k = base + lane;
            float w = 0.f;
            int j = 0;
            if (k < d) {
                int e = el[start + k];
                w = __expf((trans[e] - m) * invT) * inv;
                e_out[e] = w;
                j = segOther[e];
            }
            int cnt = (d - base < 64) ? (d - base) : 64;
            for (int q = 0; q < cnt; ++q) {
                float wq = __shfl(w, q);
                int jq = __shfl(j, q);
                acc = fmaf(wq, Vother[(long)jq * 64 + lane], acc);
            }
        }
    }
    float o = bo[lane];
#pragma unroll
    for (int k = 0; k < 64; ++k) {
        float xv = __shfl(acc, k);
        o = fmaf(xv, sW[k * 64 + lane], o);
    }
    o = (o >= 0.f) ? o : 0.01f * o;
    msg_out[(long)node * 64 + lane] = o;
}

extern "C" void kernel_launch(void* const* d_in, const int* in_sizes, int n_in,
                              void* d_out, int out_size, void* d_ws, size_t ws_size,
                              hipStream_t stream) {
    const float* node1 = (const float*)d_in[0];
    const int* seg1 = (const int*)d_in[1];
    const float* node2 = (const float*)d_in[3];
    const int* seg2 = (const int*)d_in[4];
    const float* Wk = (const float*)d_in[6];
    const float* Wv = (const float*)d_in[7];
    const float* Wo = (const float*)d_in[8];
    const float* bo = (const float*)d_in[9];

    int n1 = in_sizes[0] / 64;
    int n2 = in_sizes[3] / 64;
    int E = in_sizes[1];

    float* out = (float*)d_out;
    float* msg1 = out;
    float* msg2 = msg1 + (long)n1 * 64;
    float* e1 = msg2 + (long)n2 * 64;
    float* e2 = e1 + E;

    const float invT = 1.0f / sqrtf(64.0f);
    int nb1 = (n1 + BSZ - 1) >> BSH;
    int nb2 = (n2 + BSZ - 1) >> BSH;
    long Epad = (E + 1) & ~1L;

    // ---- fast-path layout (weights first for 16B alignment; bf16 K/V/msg) ----
    float* ws = (float*)d_ws;
    unsigned short* WkT = (unsigned short*)ws;          // 4096 ushort
    unsigned short* WvT = WkT + 4096;                   // 4096
    unsigned short* WoT = WvT + 4096;                   // 4096
    float2* csr1 = (float2*)(ws + 6144);                // E records
    float2* csr2 = csr1 + E;                            // E
    float2* tmp1 = csr2 + E;                            // E
    float2* tmp2 = tmp1 + E;                            // E
    float* trans = (float*)(tmp2 + E);                  // Epad
    float2* minv1 = (float2*)(trans + Epad);            // n1
    float2* minv2 = minv1 + n1;                         // n2
    unsigned short* Kb1 = (unsigned short*)(minv2 + n2);// n1*64 ushort
    unsigned short* Kb2 = Kb1 + (long)n1 * 64;          // n2*64
    unsigned short* Vb1 = Kb2 + (long)n2 * 64;          // n1*64
    unsigned short* Vb2 = Vb1 + (long)n1 * 64;          // n2*64
    unsigned short* msgr = Vb2 + (long)n2 * 64;         // (n1+n2)*64 ushort
    int* deg1 = (int*)(msgr + (long)(n1 + n2) * 64);    // n1
    int* deg2 = deg1 + n1;                              // n2
    int* cur1 = deg2 + n2;                              // n1
    int* cur2 = cur1 + n1;                              // n2
    int* bb1 = cur2 + n2;                               // nb1+1
    int* bb2 = bb1 + nb1 + 1;                           // nb2+1
    int* bcur1 = bb2 + nb2 + 1;                         // nb1
    int* bcur2 = bcur1 + nb1;                           // nb2
    int* bcnt1 = bcur2 + nb2;                           // nb1
    int* bcnt2 = bcnt1 + nb1;                           // nb2
    long fp_words = 6144 + 8L * E + Epad + 2L * (n1 + n2)
                  + 64L * (n1 + n2)                     // bf16 K,V both sides
                  + 32L * (n1 + n2)                     // bf16 raw msg
                  + 2L * (n1 + n2)                      // deg, cur
                  + 3L * (nb1 + nb2) + 2;
    bool fast = (E <= (1 << 20)) && (nb1 <= MAXNB) && (nb2 <= MAXNB)
             && (n1 < 65536) && (n2 < 65536) && (n1 + n2 > 0)
             && ((size_t)fp_words * 4 <= ws_size);

    if (fast) {
        int total = n1 + n2;
        int ntiles = (total + 15) / 16;
        int projBlocks = (ntiles + 3) / 4;
        prep_kernel<<<1, 256, 0, stream>>>(Wk, Wv, Wo, WkT, WvT, WoT,
                                           bcnt1, bcnt2, nb1, nb2);
        // fused: proj (MFMA) + bucket histogram (both depend only on prep)
        proj_count_kernel<<<projBlocks + 512, 256, 0, stream>>>(
            node1, n1, node2, n2, WkT, WvT, Kb1, Vb1, projBlocks,
            seg1, seg2, E, bcnt1, bcnt2, nb1, nb2);
        {
            long threads = (long)E * 8;
            int blocks = (int)((threads + 255) / 256);
            logit_kernel<<<blocks, 256, 0, stream>>>(Kb1, Kb2, seg1, seg2, trans, E);
        }
        bucket_scan_kernel<<<1, MAXNB, 0, stream>>>(bcnt1, bcnt2, bb1, bb2, bcur1, bcur2,
                                                    nb1, nb2, E);
        partition_kernel<<<(E + PT_TILE - 1) / PT_TILE, 256, 0, stream>>>(
            seg1, seg2, trans, E, bcur1, bcur2, tmp1, tmp2);
        bin2_kernel<<<nb1 + nb2, 256, 0, stream>>>(tmp1, bb1, n1, cur1, deg1, csr1,
                                                   tmp2, bb2, n2, cur2, deg2, csr2, nb1);
        gather_ms_kernel<<<(total + 3) / 4, 256, 0, stream>>>(
            n1, n2, cur1, deg1, csr1, Vb2, minv1,
            cur2, deg2, csr2, Vb1, minv2, msgr, invT);
        {
            int outBlocks = (ntiles + 3) / 4;
            int edgeBlocks = (E + 255) / 256;
            tail_kernel<<<outBlocks + edgeBlocks, 256, 0, stream>>>(
                msgr, msg1, WoT, bo, total, outBlocks,
                trans, seg1, seg2, minv1, minv2, e1, e2, E, invT);
        }
    } else {
        // fallback: R2-proven f32 path
        float* K1f = ws;
        float* V1f = K1f + (long)n1 * 64;
        float* K2f = V1f + (long)n1 * 64;
        float* V2f = K2f + (long)n2 * 64;
        float* transf = V2f + (long)n2 * 64;
        int* deg1f = (int*)(transf + E);
        int* deg2f = deg1f + n1;
        int* cur1f = deg2f + n2;
        int* cur2f = cur1f + n1;
        int* el1 = (int*)K1f;
        int* el2 = (int*)K2f;

        proj1_kernel<<<(n1 + 3) / 4, 256, 0, stream>>>(node1, n1, Wk, Wv, K1f, V1f);
        proj1_kernel<<<(n2 + 3) / 4, 256, 0, stream>>>(node2, n2, Wk, Wv, K2f, V2f);
        {
            long threads = (long)E * 16;
            int blocks = (int)((threads + 255) / 256);
            logit1_kernel<<<blocks, 256, 0, stream>>>(K1f, K2f, seg1, seg2, transf, E);
        }
        zero_deg_kernel<<<((n1 > n2 ? n1 : n2) + 255) / 256, 256, 0, stream>>>(deg1f, deg2f, n1, n2);
        hist_kernel<<<(E + 255) / 256, 256, 0, stream>>>(seg1, seg2, deg1f, deg2f, E);
        scan2_kernel<<<2, 1024, 0, stream>>>(deg1f, cur1f, n1, deg2f, cur2f, n2);
        bin_kernel<<<(E + 255) / 256, 256, 0, stream>>>(seg1, seg2, cur1f, cur2f, el1, el2, E);

        gather_out_kernel<<<(n1 + 3) / 4, 256, 0, stream>>>(
            n1, cur1f, deg1f, el1, transf, seg2, V2f, e1, msg1, Wo, bo, invT);
        gather_out_kernel<<<(n2 + 3) / 4, 256, 0, stream>>>(
            n2, cur2f, deg2f, el2, transf, seg1, V1f, e2, msg2, Wo, bo, invT);
    }
}